// Round 16
// baseline (262.740 us; speedup 1.0000x reference)
//
#include <hip/hip_runtime.h>

#define NT 256

constexpr int Bg   = 8192;      // graphs
constexpr int NPG  = 40;
constexpr int EPG  = 640;
constexpr int IN_  = 64;
constexpr int HID  = 32;
constexpr int K1   = 20;
constexpr int K2   = 10;
constexpr int OUTC = 10;
constexpr int NE   = Bg * NPG * 16;
constexpr int SH   = 36;        // padded 32-wide row stride
constexpr float EPSF = 1e-15f;

#define FMA4(acc, a, b) do { \
    float _s = (a); \
    acc.x = fmaf(_s, (b).x, acc.x); \
    acc.y = fmaf(_s, (b).y, acc.y); \
    acc.z = fmaf(_s, (b).z, acc.z); \
    acc.w = fmaf(_s, (b).w, acc.w); } while (0)

__device__ __forceinline__ float wave_red(float v) {
#pragma unroll
    for (int off = 32; off > 0; off >>= 1) v += __shfl_down(v, off, 64);
    return v;
}

// LDS overlay identical to r12/r15 (~20.9 KB -> 7 blocks/CU).
// r16 changes (14 barriers, was 16):
//  - p1b eliminated: H written directly in p1 (X-staging gone since r12, the
//    register-hold was a relic); degree sums now LDS atomic counters
//    (sdinv = raw col counts, srowsA = raw row counts; integer-valued float
//    adds -> exact & order-independent). p3 computes rsqrtf(count+1) inline.
//  - p4+p5 merged: per-row S1 logits (global w_p1, p11 pattern) + softmax
//    in-register, 40 threads.
// BUG history: r9 sSS[oo-200] negative idx; r13 p6 AS half-coverage. Both
// fixed; p6 AS uses 100 threads covering all 40 rows.
// NOTE: __launch_bounds__(256,4) — (256,6) forced 40 VGPR + 38KB spill (r4).
__global__ __launch_bounds__(NT, 4)
void mincut_fused(const float* __restrict__ x, const int* __restrict__ ei,
                  const float* __restrict__ w_c1, const float* __restrict__ b_c1,
                  const float* __restrict__ w_p1, const float* __restrict__ b_p1,
                  const float* __restrict__ w2r_, const float* __restrict__ b2_,
                  const float* __restrict__ w2o_,
                  const float* __restrict__ w_p2, const float* __restrict__ b_p2,
                  const float* __restrict__ w3r_, const float* __restrict__ b3_,
                  const float* __restrict__ w3o_,
                  const float* __restrict__ w_l1, const float* __restrict__ b_l1,
                  const float* __restrict__ w_l2, const float* __restrict__ b_l2,
                  float* __restrict__ out, float* __restrict__ wsg)
{
    __shared__ __align__(16) float sA[NPG * NPG];    // 1600
    __shared__ __align__(16) float sB[2000];
    __shared__ __align__(16) float sXd[NPG * SH];    // 1440
    __shared__ __align__(16) float sdinv[NPG];       // raw col counts
    __shared__ __align__(16) float srowsA[NPG];      // raw row counts
    __shared__ __align__(16) float srowm[NPG];
    __shared__ __align__(16) float sden[NPG];
    __shared__ __align__(16) float sc[8];
    // sc: [0]num1 [1]den1 [2]o1 [5]den2 [6]o2

    float* sA2  = sA;            // 20x20 raw
    float* sX2  = sA + 400;      // 20xSH  (p7-p12)
    float* sA3  = sA + 400;      // 10x10 raw (p13+, X2 dead)
    float* sH   = sB;            // 40xSH
    float* sS   = sB;            // 40x20
    float* sAS  = sB + 800;      // 40x20
    float* sS2  = sB + 800;      // 20x10
    float* sAS2 = sB + 1000;     // 20x10
    float* sX3  = sB + 1200;     // 10xSH
    float* sX4  = sB + 1200;     // 10xSH (after X3 dead)
    float* sSS  = sB + 1600;     // 400 (SS then SS2)
    float* sXw2r= sXd;           // 20xSH
    float* sXw2o= sXd + 720;     // 20xSH
    float* sW3r = sXd;           // 10xSH
    float* sW3o = sXd + 360;     // 10xSH

    const int g    = blockIdx.x;
    const int tid  = threadIdx.x;
    const int lane = tid & 63;
    const int wid  = tid >> 6;

    // ---- p0: edges -> regs, zero A + count arrays ----
    int er0, ec0, er1, ec1, er2 = -1, ec2 = 0;
    {
        const int eb = g * EPG, nb = g * NPG;
        int e = eb + tid;
        er0 = ei[e] - nb; ec0 = ei[NE + e] - nb;
        e += NT;
        er1 = ei[e] - nb; ec1 = ei[NE + e] - nb;
        if (tid + 2 * NT < EPG) {
            e += NT;
            er2 = ei[e] - nb; ec2 = ei[NE + e] - nb;
        }
    }
    for (int i = tid; i < NPG * NPG; i += NT) sA[i] = 0.f;
    if (tid < NPG) { sdinv[tid] = 0.f; srowsA[tid] = 0.f; }
    __syncthreads();

    // ---- p1: adj scatter + degree counters + H = X @ W1 (direct write) ----
    atomicAdd(&sA[er0 * NPG + ec0], 1.f);
    atomicAdd(&srowsA[er0], 1.f);
    atomicAdd(&sdinv[ec0], 1.f);
    atomicAdd(&sA[er1 * NPG + ec1], 1.f);
    atomicAdd(&srowsA[er1], 1.f);
    atomicAdd(&sdinv[ec1], 1.f);
    if (er2 >= 0) {
        atomicAdd(&sA[er2 * NPG + ec2], 1.f);
        atomicAdd(&srowsA[er2], 1.f);
        atomicAdd(&sdinv[ec2], 1.f);
    }

    if (tid < 160) {
        int np = tid >> 3, fq = tid & 7;
        int n0 = 2 * np, n1 = n0 + 1;
        const float4* x0 = (const float4*)(x + (size_t)g * (NPG * IN_) + n0 * IN_);
        const float4* x1 = (const float4*)(x + (size_t)g * (NPG * IN_) + n1 * IN_);
        const float4* wg = (const float4*)w_c1;
        float4 hacc0 = {0.f,0.f,0.f,0.f}, hacc1 = {0.f,0.f,0.f,0.f};
#pragma unroll 4
        for (int kk = 0; kk < IN_ / 4; kk++) {
            float4 a0 = x0[kk], a1 = x1[kk];
            float4 w0 = wg[(4*kk+0)*8 + fq];
            float4 w1 = wg[(4*kk+1)*8 + fq];
            float4 w2 = wg[(4*kk+2)*8 + fq];
            float4 w3 = wg[(4*kk+3)*8 + fq];
            FMA4(hacc0, a0.x, w0); FMA4(hacc0, a0.y, w1);
            FMA4(hacc0, a0.z, w2); FMA4(hacc0, a0.w, w3);
            FMA4(hacc1, a1.x, w0); FMA4(hacc1, a1.y, w1);
            FMA4(hacc1, a1.z, w2); FMA4(hacc1, a1.w, w3);
        }
        ((float4*)(sH + n0 * SH))[fq] = hacc0;
        ((float4*)(sH + n1 * SH))[fq] = hacc1;
    }
    __syncthreads();

    // ---- p3: Xd = relu(D^-1/2 (A+I) D^-1/2 H + b1)  [inline rsqrt] ----
    if (tid < 80) {
        int cp = tid >> 3, fq = tid & 7;
        int c0 = 4 * cp;
        float4 acc0 = {0.f,0.f,0.f,0.f}, acc1 = {0.f,0.f,0.f,0.f};
        float4 acc2 = {0.f,0.f,0.f,0.f}, acc3 = {0.f,0.f,0.f,0.f};
#pragma unroll 8
        for (int r = 0; r < NPG; r++) {
            float4 a = *(const float4*)&sA[r * NPG + c0];
            float dv = rsqrtf(sdinv[r] + 1.f);
            float4 bv = ((const float4*)(sH + r * SH))[fq];
            FMA4(acc0, a.x * dv, bv);
            FMA4(acc1, a.y * dv, bv);
            FMA4(acc2, a.z * dv, bv);
            FMA4(acc3, a.w * dv, bv);
        }
        float4 bb = ((const float4*)b_c1)[fq];
#pragma unroll
        for (int i = 0; i < 4; i++) {
            float4 acc = (i == 0) ? acc0 : (i == 1) ? acc1 : (i == 2) ? acc2 : acc3;
            int c = c0 + i;
            float d = rsqrtf(sdinv[c] + 1.f);
            float4 h = ((const float4*)(sH + c * SH))[fq];
            float4 r;
            r.x = fmaxf(fmaf(d, fmaf(d, h.x, acc.x), bb.x), 0.f);
            r.y = fmaxf(fmaf(d, fmaf(d, h.y, acc.y), bb.y), 0.f);
            r.z = fmaxf(fmaf(d, fmaf(d, h.z, acc.z), bb.z), 0.f);
            r.w = fmaxf(fmaf(d, fmaf(d, h.w, acc.w), bb.w), 0.f);
            ((float4*)(sXd + c * SH))[fq] = r;
        }
    }
    __syncthreads();

    // ---- p4: S1 logits + softmax1 fused (one thread per row, w_p1 global) --
    if (tid < NPG) {
        float acc[K1];
#pragma unroll
        for (int q = 0; q < K1; q++) acc[q] = b_p1[q];
#pragma unroll
        for (int j = 0; j < 8; j++) {
            float4 a = ((const float4*)(sXd + tid * SH))[j];
#pragma unroll
            for (int q = 0; q < K1; q++) acc[q] = fmaf(a.x, w_p1[(4*j+0) * K1 + q], acc[q]);
#pragma unroll
            for (int q = 0; q < K1; q++) acc[q] = fmaf(a.y, w_p1[(4*j+1) * K1 + q], acc[q]);
#pragma unroll
            for (int q = 0; q < K1; q++) acc[q] = fmaf(a.z, w_p1[(4*j+2) * K1 + q], acc[q]);
#pragma unroll
            for (int q = 0; q < K1; q++) acc[q] = fmaf(a.w, w_p1[(4*j+3) * K1 + q], acc[q]);
        }
        float m = -3.0e38f;
#pragma unroll
        for (int q = 0; q < K1; q++) m = fmaxf(m, acc[q]);
        float ssum = 0.f;
#pragma unroll
        for (int q = 0; q < K1; q++) { acc[q] = __expf(acc[q] - m); ssum += acc[q]; }
        float inv = 1.f / ssum;
        float4* row4 = (float4*)(sS + tid * K1);
#pragma unroll
        for (int q4 = 0; q4 < 5; q4++) {
            float4 wv;
            wv.x = acc[4*q4+0] * inv; wv.y = acc[4*q4+1] * inv;
            wv.z = acc[4*q4+2] * inv; wv.w = acc[4*q4+3] * inv;
            row4[q4] = wv;
        }
    }
    __syncthreads();

    // ---- p6: AS = A @ S (waves 0-1, ALL 40 rows) ; SS = S^T S (wave 2) ----
    if (tid < 100) {
        int np = tid / 5, lq = tid - np * 5;
        int n0 = 2 * np, n1 = n0 + 1;
        const float4* sb4 = (const float4*)sS;
        float4 acc0 = {0.f,0.f,0.f,0.f}, acc1 = {0.f,0.f,0.f,0.f};
#pragma unroll
        for (int m4 = 0; m4 < NPG / 4; m4++) {
            float4 a0 = *(const float4*)&sA[n0 * NPG + 4 * m4];
            float4 a1 = *(const float4*)&sA[n1 * NPG + 4 * m4];
            float4 b0 = sb4[(4*m4+0)*5 + lq];
            float4 b1 = sb4[(4*m4+1)*5 + lq];
            float4 b2v = sb4[(4*m4+2)*5 + lq];
            float4 b3v = sb4[(4*m4+3)*5 + lq];
            FMA4(acc0, a0.x, b0); FMA4(acc0, a0.y, b1);
            FMA4(acc0, a0.z, b2v); FMA4(acc0, a0.w, b3v);
            FMA4(acc1, a1.x, b0); FMA4(acc1, a1.y, b1);
            FMA4(acc1, a1.z, b2v); FMA4(acc1, a1.w, b3v);
        }
        ((float4*)(sAS + n0 * K1))[lq] = acc0;
        ((float4*)(sAS + n1 * K1))[lq] = acc1;
    } else if (tid >= 128 && tid < 178) {
        int oo = tid - 128;
        int kp = oo / 5, lq = oo - kp * 5;
        int k0 = 2 * kp, k1 = k0 + 1;
        float4 acc0 = {0.f,0.f,0.f,0.f}, acc1 = {0.f,0.f,0.f,0.f};
#pragma unroll 8
        for (int n = 0; n < NPG; n++) {
            float2 s2v = *(const float2*)&sS[n * K1 + k0];
            float4 bv = ((const float4*)(sS + n * K1))[lq];
            FMA4(acc0, s2v.x, bv); FMA4(acc1, s2v.y, bv);
        }
        ((float4*)(sSS + k0 * K1))[lq] = acc0;
        ((float4*)(sSS + k1 * K1))[lq] = acc1;
    }
    __syncthreads();

    // ---- p7: A2 4-k (wave0) ; X2 4-k (wave1) ; den1 (wave2, f4) ----
    if (tid < 25) {
        int kp = tid / 5, lq = tid - kp * 5;
        int k0 = 4 * kp;
        float4 acc0 = {0.f,0.f,0.f,0.f}, acc1 = {0.f,0.f,0.f,0.f};
        float4 acc2 = {0.f,0.f,0.f,0.f}, acc3 = {0.f,0.f,0.f,0.f};
#pragma unroll 8
        for (int n = 0; n < NPG; n++) {
            float4 sv = *(const float4*)&sS[n * K1 + k0];
            float4 bv = ((const float4*)(sAS + n * K1))[lq];
            FMA4(acc0, sv.x, bv); FMA4(acc1, sv.y, bv);
            FMA4(acc2, sv.z, bv); FMA4(acc3, sv.w, bv);
        }
        ((float4*)(sA2 + (k0+0) * K1))[lq] = acc0;
        ((float4*)(sA2 + (k0+1) * K1))[lq] = acc1;
        ((float4*)(sA2 + (k0+2) * K1))[lq] = acc2;
        ((float4*)(sA2 + (k0+3) * K1))[lq] = acc3;
    } else if (tid >= 64 && tid < 104) {
        int oo = tid - 64;
        int kp = oo >> 3, fq = oo & 7;
        int k0 = 4 * kp;
        float4 acc0 = {0.f,0.f,0.f,0.f}, acc1 = {0.f,0.f,0.f,0.f};
        float4 acc2 = {0.f,0.f,0.f,0.f}, acc3 = {0.f,0.f,0.f,0.f};
#pragma unroll 8
        for (int n = 0; n < NPG; n++) {
            float4 sv = *(const float4*)&sS[n * K1 + k0];
            float4 bv = ((const float4*)(sXd + n * SH))[fq];
            FMA4(acc0, sv.x, bv); FMA4(acc1, sv.y, bv);
            FMA4(acc2, sv.z, bv); FMA4(acc3, sv.w, bv);
        }
        ((float4*)(sX2 + (k0+0) * SH))[fq] = acc0;
        ((float4*)(sX2 + (k0+1) * SH))[fq] = acc1;
        ((float4*)(sX2 + (k0+2) * SH))[fq] = acc2;
        ((float4*)(sX2 + (k0+3) * SH))[fq] = acc3;
    } else if (tid >= 128 && tid < 168) {
        int n = tid - 128;
        float s2 = 0.f;
#pragma unroll
        for (int j = 0; j < 5; j++) {
            float4 v = ((const float4*)(sS + n * K1))[j];
            s2 = fmaf(v.x, v.x, s2); s2 = fmaf(v.y, v.y, s2);
            s2 = fmaf(v.z, v.z, s2); s2 = fmaf(v.w, v.w, s2);
        }
        sden[n] = srowsA[n] * s2;
    }
    __syncthreads();

    // ---- p8: stats (waves 0-2) + XW2r/XW2o matmuls (f4 X2 reads) ----
    if (wid == 0) {              // closed-form ortho1 from SS
        float f = 0.f, tr = 0.f;
        for (int i = lane; i < K1 * K1; i += 64) {
            float t = sSS[i];
            f = fmaf(t, t, f);
            if (i % (K1 + 1) == 0) tr += t;
        }
        f = wave_red(f); tr = wave_red(tr);
        if (lane == 0)
            sc[2] = sqrtf(fmaxf(2.f - 2.f * tr / (sqrtf(f) * 4.47213595499958f), 0.f));
    } else if (wid == 1) {       // num1 = trace(A2) ; rownorm1 (A2 kept raw)
        float v = 0.f;
        if (lane < K1) {
            float s = 0.f;
#pragma unroll
            for (int j = 0; j < 5; j++) {
                float4 a = *(const float4*)&sA2[lane * K1 + 4*j];
                s += a.x + a.y + a.z + a.w;
            }
            float d = sA2[lane * (K1 + 1)];
            srowm[lane] = 1.f / (sqrtf(s - d) + EPSF);
            v = d;
        }
        v = wave_red(v);
        if (lane == 0) sc[0] = v;
    } else if (wid == 2) {       // den1
        float v = (lane < NPG) ? sden[lane] : 0.f;
        v = wave_red(v);
        if (lane == 0) sc[1] = v;
    }
    for (int o = tid; o < 320; o += NT) {
        int first = o < 160; int m = first ? o : o - 160;
        int n = m >> 3, fq = m & 7;
        const float4* wg = (const float4*)(first ? w2r_ : w2o_);
        float4 acc = {0.f,0.f,0.f,0.f};
#pragma unroll
        for (int j = 0; j < 8; j++) {
            float4 a = ((const float4*)(sX2 + n * SH))[j];
            float4 w0 = wg[(4*j+0) * 8 + fq];
            float4 w1 = wg[(4*j+1) * 8 + fq];
            float4 w2 = wg[(4*j+2) * 8 + fq];
            float4 w3 = wg[(4*j+3) * 8 + fq];
            FMA4(acc, a.x, w0); FMA4(acc, a.y, w1);
            FMA4(acc, a.z, w2); FMA4(acc, a.w, w3);
        }
        ((float4*)((first ? sXw2r : sXw2o) + n * SH))[fq] = acc;
    }
    __syncthreads();

    // ---- pC: X2' = relu(adj1n @ XW2r + XW2o + b2)  [f4 A2/srowm, diag-sub] --
    if (tid < 160) {
        int k = tid >> 3, fq = tid & 7;
        float4 a[5];
#pragma unroll
        for (int j = 0; j < 5; j++) {
            float4 av = *(const float4*)&sA2[k * K1 + 4*j];
            float4 rm = *(const float4*)&srowm[4*j];
            a[j].x = av.x * rm.x; a[j].y = av.y * rm.y;
            a[j].z = av.z * rm.z; a[j].w = av.w * rm.w;
        }
        float4 acc = {0.f,0.f,0.f,0.f};
#pragma unroll
        for (int j = 0; j < 5; j++) {
            float4 w0 = ((const float4*)(sXw2r + (4*j+0) * SH))[fq];
            float4 w1 = ((const float4*)(sXw2r + (4*j+1) * SH))[fq];
            float4 w2 = ((const float4*)(sXw2r + (4*j+2) * SH))[fq];
            float4 w3 = ((const float4*)(sXw2r + (4*j+3) * SH))[fq];
            FMA4(acc, a[j].x, w0); FMA4(acc, a[j].y, w1);
            FMA4(acc, a[j].z, w2); FMA4(acc, a[j].w, w3);
        }
        float adiag = sA2[k * (K1 + 1)] * srowm[k];
        float4 wk = ((const float4*)(sXw2r + k * SH))[fq];
        acc.x -= adiag * wk.x; acc.y -= adiag * wk.y;
        acc.z -= adiag * wk.z; acc.w -= adiag * wk.w;
        float4 bb = ((const float4*)b2_)[fq];
        float4 oo = ((const float4*)(sXw2o + k * SH))[fq];
        float rk = srowm[k];
        float4 r;
        r.x = fmaxf(fmaf(rk, acc.x, oo.x + bb.x), 0.f);
        r.y = fmaxf(fmaf(rk, acc.y, oo.y + bb.y), 0.f);
        r.z = fmaxf(fmaf(rk, acc.z, oo.z + bb.z), 0.f);
        r.w = fmaxf(fmaf(rk, acc.w, oo.w + bb.w), 0.f);
        ((float4*)(sX2 + k * SH))[fq] = r;
    }
    __syncthreads();

    // ---- p11: S2 logits + softmax2 fused (f4 reads, f2 writes) ----
    if (tid < K1) {
        float acc[K2];
#pragma unroll
        for (int q = 0; q < K2; q++) acc[q] = b_p2[q];
#pragma unroll
        for (int j = 0; j < 8; j++) {
            float4 a = ((const float4*)(sX2 + tid * SH))[j];
#pragma unroll
            for (int q = 0; q < K2; q++) acc[q] = fmaf(a.x, w_p2[(4*j+0) * K2 + q], acc[q]);
#pragma unroll
            for (int q = 0; q < K2; q++) acc[q] = fmaf(a.y, w_p2[(4*j+1) * K2 + q], acc[q]);
#pragma unroll
            for (int q = 0; q < K2; q++) acc[q] = fmaf(a.z, w_p2[(4*j+2) * K2 + q], acc[q]);
#pragma unroll
            for (int q = 0; q < K2; q++) acc[q] = fmaf(a.w, w_p2[(4*j+3) * K2 + q], acc[q]);
        }
        float m = -3.0e38f;
#pragma unroll
        for (int q = 0; q < K2; q++) m = fmaxf(m, acc[q]);
        float ssum = 0.f;
#pragma unroll
        for (int q = 0; q < K2; q++) { acc[q] = __expf(acc[q] - m); ssum += acc[q]; }
        float inv = 1.f / ssum;
#pragma unroll
        for (int q2 = 0; q2 < 5; q2++) {
            float2 wv; wv.x = acc[2*q2] * inv; wv.y = acc[2*q2+1] * inv;
            *(float2*)&sS2[tid * K2 + 2*q2] = wv;
        }
    }
    __syncthreads();

    // ---- p12: AS2 (waves 0-1) ; SS2+den2 (wave 2) ; X3 (wave 3) ----
    if (tid < 100) {             // AS2: (n, l-pair), f4 A2/srowm + f2 S2
        int n = tid / 5, lp = tid - (tid / 5) * 5;
        int l0 = 2 * lp;
        float accx = 0.f, accy = 0.f;
#pragma unroll
        for (int j = 0; j < 5; j++) {
            float4 av = *(const float4*)&sA2[n * K1 + 4*j];
            float4 rm = *(const float4*)&srowm[4*j];
            float2 s0 = *(const float2*)&sS2[(4*j+0) * K2 + l0];
            float2 s1 = *(const float2*)&sS2[(4*j+1) * K2 + l0];
            float2 s2v = *(const float2*)&sS2[(4*j+2) * K2 + l0];
            float2 s3 = *(const float2*)&sS2[(4*j+3) * K2 + l0];
            float c0 = av.x * rm.x, c1 = av.y * rm.y, c2 = av.z * rm.z, c3 = av.w * rm.w;
            accx = fmaf(c0, s0.x, accx); accy = fmaf(c0, s0.y, accy);
            accx = fmaf(c1, s1.x, accx); accy = fmaf(c1, s1.y, accy);
            accx = fmaf(c2, s2v.x, accx); accy = fmaf(c2, s2v.y, accy);
            accx = fmaf(c3, s3.x, accx); accy = fmaf(c3, s3.y, accy);
        }
        float cd = sA2[n * (K1 + 1)] * srowm[n];
        float2 sn = *(const float2*)&sS2[n * K2 + l0];
        accx -= cd * sn.x; accy -= cd * sn.y;
        float rn = srowm[n];
        float2 wv; wv.x = accx * rn; wv.y = accy * rn;
        *(float2*)&sAS2[n * K2 + l0] = wv;
    } else if (tid >= 128 && tid < 153) {   // SS2: (k-pair, l-pair)
        int oo = tid - 128;
        int kp = oo / 5, lp = oo - kp * 5;
        int k0 = 2 * kp, l0 = 2 * lp;
        float a00 = 0.f, a01 = 0.f, a10 = 0.f, a11 = 0.f;
#pragma unroll
        for (int n = 0; n < K1; n++) {
            float2 a = *(const float2*)&sS2[n * K2 + k0];
            float2 b = *(const float2*)&sS2[n * K2 + l0];
            a00 = fmaf(a.x, b.x, a00); a01 = fmaf(a.x, b.y, a01);
            a10 = fmaf(a.y, b.x, a10); a11 = fmaf(a.y, b.y, a11);
        }
        sSS[(k0+0) * K2 + l0]     = a00;
        sSS[(k0+0) * K2 + l0 + 1] = a01;
        sSS[(k0+1) * K2 + l0]     = a10;
        sSS[(k0+1) * K2 + l0 + 1] = a11;
    } else if (tid >= 160 && tid < 180) {   // den2 terms
        int n = tid - 160;
        float da = 0.f;
#pragma unroll
        for (int j = 0; j < 5; j++) {
            float4 av = *(const float4*)&sA2[n * K1 + 4*j];
            float4 rm = *(const float4*)&srowm[4*j];
            da = fmaf(av.x, rm.x, da); da = fmaf(av.y, rm.y, da);
            da = fmaf(av.z, rm.z, da); da = fmaf(av.w, rm.w, da);
        }
        da -= sA2[n * (K1 + 1)] * srowm[n];
        da *= srowm[n];
        float s2 = 0.f;
#pragma unroll
        for (int q2 = 0; q2 < 5; q2++) {
            float2 v = *(const float2*)&sS2[n * K2 + 2*q2];
            s2 = fmaf(v.x, v.x, s2); s2 = fmaf(v.y, v.y, s2);
        }
        sden[n] = da * s2;
    } else if (tid >= 192 && tid < 232) {   // X3 = S2^T X2' (2-k tiles)
        int oo = tid - 192;
        int kp = oo >> 3, fq = oo & 7;
        int k0 = 2 * kp;
        float4 acc0 = {0.f,0.f,0.f,0.f}, acc1 = {0.f,0.f,0.f,0.f};
#pragma unroll
        for (int n = 0; n < K1; n++) {
            float2 sv = *(const float2*)&sS2[n * K2 + k0];
            float4 bv = ((const float4*)(sX2 + n * SH))[fq];
            FMA4(acc0, sv.x, bv); FMA4(acc1, sv.y, bv);
        }
        ((float4*)(sX3 + (k0+0) * SH))[fq] = acc0;
        ((float4*)(sX3 + (k0+1) * SH))[fq] = acc1;
    }
    __syncthreads();

    // ---- p13: A3 = S2^T AS2 f2-tiled (wave0) ; den2 (w2) ; ortho2 (w3) ----
    if (tid < 25) {
        int kp = tid / 5, lp = tid - kp * 5;
        int k0 = 2 * kp, l0 = 2 * lp;
        float a00 = 0.f, a01 = 0.f, a10 = 0.f, a11 = 0.f;
#pragma unroll
        for (int n = 0; n < K1; n++) {
            float2 sv = *(const float2*)&sS2[n * K2 + k0];
            float2 av = *(const float2*)&sAS2[n * K2 + l0];
            a00 = fmaf(sv.x, av.x, a00); a01 = fmaf(sv.x, av.y, a01);
            a10 = fmaf(sv.y, av.x, a10); a11 = fmaf(sv.y, av.y, a11);
        }
        sA3[(k0+0) * K2 + l0]     = a00;
        sA3[(k0+0) * K2 + l0 + 1] = a01;
        sA3[(k0+1) * K2 + l0]     = a10;
        sA3[(k0+1) * K2 + l0 + 1] = a11;
    } else if (wid == 2) {
        float v = (lane < K1) ? sden[lane] : 0.f;
        v = wave_red(v);
        if (lane == 0) sc[5] = v;
    } else if (wid == 3) {
        float f = 0.f, tr = 0.f;
        for (int i = lane; i < K2 * K2; i += 64) {
            float t = sSS[i];
            f = fmaf(t, t, f);
            if (i % (K2 + 1) == 0) tr += t;
        }
        f = wave_red(f); tr = wave_red(tr);
        if (lane == 0)
            sc[6] = sqrtf(fmaxf(2.f - 2.f * tr / (sqrtf(f) * 3.1622776601683795f), 0.f));
    }
    __syncthreads();

    // ---- p14: XW3r/XW3o (f4 X3 reads) ; rownorm2 + loss (wave 3) ----
    if (tid < 160) {
        bool first = (tid < 80);
        int oo = first ? tid : tid - 80;
        int n = oo >> 3, fq = oo & 7;
        const float4* wg = (const float4*)(first ? w3r_ : w3o_);
        float4 acc = {0.f,0.f,0.f,0.f};
#pragma unroll
        for (int j = 0; j < 8; j++) {
            float4 a = ((const float4*)(sX3 + n * SH))[j];
            float4 w0 = wg[(4*j+0) * 8 + fq];
            float4 w1 = wg[(4*j+1) * 8 + fq];
            float4 w2 = wg[(4*j+2) * 8 + fq];
            float4 w3 = wg[(4*j+3) * 8 + fq];
            FMA4(acc, a.x, w0); FMA4(acc, a.y, w1);
            FMA4(acc, a.z, w2); FMA4(acc, a.w, w3);
        }
        if (first) ((float4*)(sW3r + n * SH))[fq] = acc;
        else       ((float4*)(sW3o + n * SH))[fq] = acc;
    } else if (tid >= 192 && tid < 202) {
        int l = tid - 192;
        float s = 0.f;
#pragma unroll
        for (int j = 0; j < 5; j++) {
            float2 a = *(const float2*)&sA3[l * K2 + 2*j];
            s += a.x + a.y;
        }
        s -= sA3[l * (K2 + 1)];
        srowm[l] = 1.f / (sqrtf(s) + EPSF);
    } else if (tid == 202) {
        float num2 = 0.f;
#pragma unroll
        for (int k = 0; k < K2; k++) num2 += sA3[k * (K2 + 1)];
        wsg[g] = -(sc[0] / sc[1]) + sc[2] - num2 / sc[5] + sc[6];
    }
    __syncthreads();

    // ---- p15: X4 = adj2n @ XW3r + XW3o + b3  [f2 A3/srowm, diag-sub] ----
    if (tid < 80) {
        int k = tid >> 3, fq = tid & 7;
        float4 acc = {0.f,0.f,0.f,0.f};
#pragma unroll
        for (int j = 0; j < 5; j++) {
            float2 av = *(const float2*)&sA3[k * K2 + 2*j];
            float2 rm = *(const float2*)&srowm[2*j];
            float c0 = av.x * rm.x, c1 = av.y * rm.y;
            float4 w0 = ((const float4*)(sW3r + (2*j+0) * SH))[fq];
            float4 w1 = ((const float4*)(sW3r + (2*j+1) * SH))[fq];
            FMA4(acc, c0, w0); FMA4(acc, c1, w1);
        }
        float adiag = sA3[k * (K2 + 1)] * srowm[k];
        float4 wk = ((const float4*)(sW3r + k * SH))[fq];
        acc.x -= adiag * wk.x; acc.y -= adiag * wk.y;
        acc.z -= adiag * wk.z; acc.w -= adiag * wk.w;
        float4 bb = ((const float4*)b3_)[fq];
        float4 oo = ((const float4*)(sW3o + k * SH))[fq];
        float rk = srowm[k];
        float4 r;
        r.x = fmaf(rk, acc.x, oo.x + bb.x);
        r.y = fmaf(rk, acc.y, oo.y + bb.y);
        r.z = fmaf(rk, acc.z, oo.z + bb.z);
        r.w = fmaf(rk, acc.w, oo.w + bb.w);
        ((float4*)(sX4 + k * SH))[fq] = r;
    }
    __syncthreads();

    // ---- p16: mean pool + MLP head (wave 0, shuffle-based) ----
    if (wid == 0) {
        int f = lane & 31;
        float pool = 0.f;
#pragma unroll
        for (int n = 0; n < K2; n++) pool += sX4[n * SH + f];
        pool *= (1.f / K2);
        float acc = b_l1[f];
#pragma unroll
        for (int j = 0; j < HID; j++)
            acc = fmaf(__shfl(pool, j, 64), w_l1[j * HID + f], acc);
        float t1 = fmaxf(acc, 0.f);
        int o = (lane < OUTC) ? lane : 0;
        float acc2 = b_l2[o];
#pragma unroll
        for (int j = 0; j < HID; j++)
            acc2 = fmaf(__shfl(t1, j, 64), w_l2[j * OUTC + o], acc2);
        if (lane < OUTC) out[(size_t)g * OUTC + lane] = acc2;
    }
}

__global__ void loss_reduce(const float* __restrict__ wsg, float* __restrict__ out)
{
    __shared__ float sred[4];
    int tid = threadIdx.x;
    float s = 0.f;
    for (int i = tid; i < Bg; i += NT) s += wsg[i];
    s = wave_red(s);
    if ((tid & 63) == 0) sred[tid >> 6] = s;
    __syncthreads();
    if (tid == 0) out[(size_t)Bg * OUTC] = (sred[0] + sred[1] + sred[2] + sred[3]) * (1.f / Bg);
}

extern "C" void kernel_launch(void* const* d_in, const int* in_sizes, int n_in,
                              void* d_out, int out_size, void* d_ws, size_t ws_size,
                              hipStream_t stream)
{
    const float* x    = (const float*)d_in[0];
    const int*   ei   = (const int*)  d_in[1];
    // d_in[2] = batch (unused: graphs are contiguous blocks of NPG nodes)
    const float* w_c1 = (const float*)d_in[3];
    const float* b_c1 = (const float*)d_in[4];
    const float* w_p1 = (const float*)d_in[5];
    const float* b_p1 = (const float*)d_in[6];
    const float* w2r  = (const float*)d_in[7];
    const float* b2   = (const float*)d_in[8];
    const float* w2o  = (const float*)d_in[9];
    const float* w_p2 = (const float*)d_in[10];
    const float* b_p2 = (const float*)d_in[11];
    const float* w3r  = (const float*)d_in[12];
    const float* b3   = (const float*)d_in[13];
    const float* w3o  = (const float*)d_in[14];
    const float* w_l1 = (const float*)d_in[15];
    const float* b_l1 = (const float*)d_in[16];
    const float* w_l2 = (const float*)d_in[17];
    const float* b_l2 = (const float*)d_in[18];
    float* out = (float*)d_out;
    float* wsg = (float*)d_ws;

    hipLaunchKernelGGL(mincut_fused, dim3(Bg), dim3(NT), 0, stream,
                       x, ei, w_c1, b_c1, w_p1, b_p1, w2r, b2, w2o,
                       w_p2, b_p2, w3r, b3, w3o, w_l1, b_l1, w_l2, b_l2,
                       out, wsg);
    hipLaunchKernelGGL(loss_reduce, dim3(1), dim3(NT), 0, stream, wsg, out);
}

// Round 17
// 233.341 us; speedup vs baseline: 1.1260x; 1.1260x over previous
//
#include <hip/hip_runtime.h>

#define NT 256

constexpr int Bg   = 8192;      // graphs
constexpr int NPG  = 40;
constexpr int EPG  = 640;
constexpr int IN_  = 64;
constexpr int HID  = 32;
constexpr int K1   = 20;
constexpr int K2   = 10;
constexpr int OUTC = 10;
constexpr int NE   = Bg * NPG * 16;
constexpr int SH   = 36;        // padded 32-wide row stride
constexpr float EPSF = 1e-15f;

#define FMA4(acc, a, b) do { \
    float _s = (a); \
    acc.x = fmaf(_s, (b).x, acc.x); \
    acc.y = fmaf(_s, (b).y, acc.y); \
    acc.z = fmaf(_s, (b).z, acc.z); \
    acc.w = fmaf(_s, (b).w, acc.w); } while (0)

__device__ __forceinline__ float wave_red(float v) {
#pragma unroll
    for (int off = 32; off > 0; off >>= 1) v += __shfl_down(v, off, 64);
    return v;
}

// r17 = exact revert to r15 (232.9 us best): r16's two changes both regressed
// (3x LDS atomics into 40-slot counters = ~16-way contention; p4 fusion
// serialized to 40 lanes x 640 scalar broadcast loads). Keep r15's p1b
// (conflict-free f4 degree sums) and split p4/p5.
// LDS overlay (~20.9 KB -> 7 blocks/CU); f4/f2 vectorized LDS reads; 4-wide
// register tiles in p3/p7; diag via full-sum+subtract; wave-aligned tasks.
// BUG history: r9 sSS[oo-200]; r13 p6 AS half-coverage — both fixed here.
// NOTE: __launch_bounds__(256,4) — (256,6) forced 40 VGPR + 38KB spill (r4).
__global__ __launch_bounds__(NT, 4)
void mincut_fused(const float* __restrict__ x, const int* __restrict__ ei,
                  const float* __restrict__ w_c1, const float* __restrict__ b_c1,
                  const float* __restrict__ w_p1, const float* __restrict__ b_p1,
                  const float* __restrict__ w2r_, const float* __restrict__ b2_,
                  const float* __restrict__ w2o_,
                  const float* __restrict__ w_p2, const float* __restrict__ b_p2,
                  const float* __restrict__ w3r_, const float* __restrict__ b3_,
                  const float* __restrict__ w3o_,
                  const float* __restrict__ w_l1, const float* __restrict__ b_l1,
                  const float* __restrict__ w_l2, const float* __restrict__ b_l2,
                  float* __restrict__ out, float* __restrict__ wsg)
{
    __shared__ __align__(16) float sA[NPG * NPG];    // 1600
    __shared__ __align__(16) float sB[2000];
    __shared__ __align__(16) float sXd[NPG * SH];    // 1440
    __shared__ __align__(16) float sdinv[NPG];
    __shared__ __align__(16) float srowsA[NPG];
    __shared__ __align__(16) float srowm[NPG];
    __shared__ __align__(16) float sden[NPG];
    __shared__ __align__(16) float sc[8];
    // sc: [0]num1 [1]den1 [2]o1 [5]den2 [6]o2

    float* sA2  = sA;            // 20x20 raw
    float* sX2  = sA + 400;      // 20xSH  (p7-p12)
    float* sA3  = sA + 400;      // 10x10 raw (p13+, X2 dead)
    float* sH   = sB;            // 40xSH
    float* sS   = sB;            // 40x20
    float* sAS  = sB + 800;      // 40x20
    float* sS2  = sB + 800;      // 20x10
    float* sAS2 = sB + 1000;     // 20x10
    float* sX3  = sB + 1200;     // 10xSH
    float* sX4  = sB + 1200;     // 10xSH (after X3 dead)
    float* sSS  = sB + 1600;     // 400 (SS then SS2)
    float* sXw2r= sXd;           // 20xSH
    float* sXw2o= sXd + 720;     // 20xSH
    float* sW3r = sXd;           // 10xSH
    float* sW3o = sXd + 360;     // 10xSH

    const int g    = blockIdx.x;
    const int tid  = threadIdx.x;
    const int lane = tid & 63;
    const int wid  = tid >> 6;

    // ---- p0: edges -> regs, zero A ----
    int er0, ec0, er1, ec1, er2 = -1, ec2 = 0;
    {
        const int eb = g * EPG, nb = g * NPG;
        int e = eb + tid;
        er0 = ei[e] - nb; ec0 = ei[NE + e] - nb;
        e += NT;
        er1 = ei[e] - nb; ec1 = ei[NE + e] - nb;
        if (tid + 2 * NT < EPG) {
            e += NT;
            er2 = ei[e] - nb; ec2 = ei[NE + e] - nb;
        }
    }
    for (int i = tid; i < NPG * NPG; i += NT) sA[i] = 0.f;
    __syncthreads();

    // ---- p1: adj scatter + H = X @ W1 (X from global, held in registers) ----
    atomicAdd(&sA[er0 * NPG + ec0], 1.f);
    atomicAdd(&sA[er1 * NPG + ec1], 1.f);
    if (er2 >= 0) atomicAdd(&sA[er2 * NPG + ec2], 1.f);

    float4 hacc0 = {0.f,0.f,0.f,0.f}, hacc1 = {0.f,0.f,0.f,0.f};
    if (tid < 160) {
        int np = tid >> 3, fq = tid & 7;
        int n0 = 2 * np, n1 = n0 + 1;
        const float4* x0 = (const float4*)(x + (size_t)g * (NPG * IN_) + n0 * IN_);
        const float4* x1 = (const float4*)(x + (size_t)g * (NPG * IN_) + n1 * IN_);
        const float4* wg = (const float4*)w_c1;
#pragma unroll 4
        for (int kk = 0; kk < IN_ / 4; kk++) {
            float4 a0 = x0[kk], a1 = x1[kk];
            float4 w0 = wg[(4*kk+0)*8 + fq];
            float4 w1 = wg[(4*kk+1)*8 + fq];
            float4 w2 = wg[(4*kk+2)*8 + fq];
            float4 w3 = wg[(4*kk+3)*8 + fq];
            FMA4(hacc0, a0.x, w0); FMA4(hacc0, a0.y, w1);
            FMA4(hacc0, a0.z, w2); FMA4(hacc0, a0.w, w3);
            FMA4(hacc1, a1.x, w0); FMA4(hacc1, a1.y, w1);
            FMA4(hacc1, a1.z, w2); FMA4(hacc1, a1.w, w3);
        }
    }
    __syncthreads();

    // ---- p1b: write H (waves 0-2) ; degrees on wave 3 (f4 reads) ----
    if (tid < 160) {
        int np = tid >> 3, fq = tid & 7;
        int n0 = 2 * np, n1 = n0 + 1;
        ((float4*)(sH + n0 * SH))[fq] = hacc0;
        ((float4*)(sH + n1 * SH))[fq] = hacc1;
    } else if (tid >= 192 && tid < 202) {      // col sums -> dinv (4 cols each)
        int c0 = 4 * (tid - 192);
        float4 s = {0.f,0.f,0.f,0.f};
#pragma unroll 8
        for (int r = 0; r < NPG; r++) {
            float4 a = *(const float4*)&sA[r * NPG + c0];
            s.x += a.x; s.y += a.y; s.z += a.z; s.w += a.w;
        }
        sdinv[c0+0] = rsqrtf(s.x + 1.f);
        sdinv[c0+1] = rsqrtf(s.y + 1.f);
        sdinv[c0+2] = rsqrtf(s.z + 1.f);
        sdinv[c0+3] = rsqrtf(s.w + 1.f);
    } else if (tid >= 202 && tid < 212) {      // row sums (4 rows each)
        int r0 = 4 * (tid - 202);
        float s0 = 0.f, s1 = 0.f, s2 = 0.f, s3 = 0.f;
#pragma unroll
        for (int j = 0; j < 10; j++) {
            float4 a0 = *(const float4*)&sA[(r0+0) * NPG + 4*j];
            float4 a1 = *(const float4*)&sA[(r0+1) * NPG + 4*j];
            float4 a2 = *(const float4*)&sA[(r0+2) * NPG + 4*j];
            float4 a3 = *(const float4*)&sA[(r0+3) * NPG + 4*j];
            s0 += a0.x + a0.y + a0.z + a0.w;
            s1 += a1.x + a1.y + a1.z + a1.w;
            s2 += a2.x + a2.y + a2.z + a2.w;
            s3 += a3.x + a3.y + a3.z + a3.w;
        }
        srowsA[r0+0] = s0; srowsA[r0+1] = s1;
        srowsA[r0+2] = s2; srowsA[r0+3] = s3;
    }
    __syncthreads();

    // ---- p3: Xd = relu(D^-1/2 (A+I) D^-1/2 H + b1)  [4-col tiles, f4 A] ----
    if (tid < 80) {
        int cp = tid >> 3, fq = tid & 7;
        int c0 = 4 * cp;
        float4 acc0 = {0.f,0.f,0.f,0.f}, acc1 = {0.f,0.f,0.f,0.f};
        float4 acc2 = {0.f,0.f,0.f,0.f}, acc3 = {0.f,0.f,0.f,0.f};
#pragma unroll 8
        for (int r = 0; r < NPG; r++) {
            float4 a = *(const float4*)&sA[r * NPG + c0];
            float dv = sdinv[r];
            float4 bv = ((const float4*)(sH + r * SH))[fq];
            FMA4(acc0, a.x * dv, bv);
            FMA4(acc1, a.y * dv, bv);
            FMA4(acc2, a.z * dv, bv);
            FMA4(acc3, a.w * dv, bv);
        }
        float4 bb = ((const float4*)b_c1)[fq];
#pragma unroll
        for (int i = 0; i < 4; i++) {
            float4 acc = (i == 0) ? acc0 : (i == 1) ? acc1 : (i == 2) ? acc2 : acc3;
            int c = c0 + i;
            float d = sdinv[c];
            float4 h = ((const float4*)(sH + c * SH))[fq];
            float4 r;
            r.x = fmaxf(fmaf(d, fmaf(d, h.x, acc.x), bb.x), 0.f);
            r.y = fmaxf(fmaf(d, fmaf(d, h.y, acc.y), bb.y), 0.f);
            r.z = fmaxf(fmaf(d, fmaf(d, h.z, acc.z), bb.z), 0.f);
            r.w = fmaxf(fmaf(d, fmaf(d, h.w, acc.w), bb.w), 0.f);
            ((float4*)(sXd + c * SH))[fq] = r;
        }
    }
    __syncthreads();

    // ---- p4: S1 logits = Xd @ Wp1 + bp1  (f4 Xd reads) ----
    if (tid < 100) {
        int np = tid / 5, lq = tid - np * 5;
        int n0 = 2 * np, n1 = n0 + 1;
        const float4* wg = (const float4*)w_p1;
        float4 bb = ((const float4*)b_p1)[lq];
        float4 acc0 = bb, acc1 = bb;
#pragma unroll
        for (int j = 0; j < 8; j++) {
            float4 a0 = ((const float4*)(sXd + n0 * SH))[j];
            float4 a1 = ((const float4*)(sXd + n1 * SH))[j];
            float4 w0 = wg[(4*j+0) * 5 + lq];
            float4 w1 = wg[(4*j+1) * 5 + lq];
            float4 w2 = wg[(4*j+2) * 5 + lq];
            float4 w3 = wg[(4*j+3) * 5 + lq];
            FMA4(acc0, a0.x, w0); FMA4(acc0, a0.y, w1);
            FMA4(acc0, a0.z, w2); FMA4(acc0, a0.w, w3);
            FMA4(acc1, a1.x, w0); FMA4(acc1, a1.y, w1);
            FMA4(acc1, a1.z, w2); FMA4(acc1, a1.w, w3);
        }
        ((float4*)(sS + n0 * K1))[lq] = acc0;
        ((float4*)(sS + n1 * K1))[lq] = acc1;
    }
    __syncthreads();

    // ---- p5: softmax1 (f4 row I/O) ----
    if (tid < NPG) {
        float4* row4 = (float4*)(sS + tid * K1);
        float4 v[5];
        float m = -3.0e38f;
#pragma unroll
        for (int j = 0; j < 5; j++) {
            v[j] = row4[j];
            m = fmaxf(m, fmaxf(fmaxf(v[j].x, v[j].y), fmaxf(v[j].z, v[j].w)));
        }
        float ssum = 0.f;
#pragma unroll
        for (int j = 0; j < 5; j++) {
            v[j].x = __expf(v[j].x - m); v[j].y = __expf(v[j].y - m);
            v[j].z = __expf(v[j].z - m); v[j].w = __expf(v[j].w - m);
            ssum += v[j].x + v[j].y + v[j].z + v[j].w;
        }
        float inv = 1.f / ssum;
#pragma unroll
        for (int j = 0; j < 5; j++) {
            v[j].x *= inv; v[j].y *= inv; v[j].z *= inv; v[j].w *= inv;
            row4[j] = v[j];
        }
    }
    __syncthreads();

    // ---- p6: AS = A @ S (waves 0-1, ALL 40 rows) ; SS = S^T S (wave 2) ----
    if (tid < 100) {
        int np = tid / 5, lq = tid - np * 5;
        int n0 = 2 * np, n1 = n0 + 1;
        const float4* sb4 = (const float4*)sS;
        float4 acc0 = {0.f,0.f,0.f,0.f}, acc1 = {0.f,0.f,0.f,0.f};
#pragma unroll
        for (int m4 = 0; m4 < NPG / 4; m4++) {
            float4 a0 = *(const float4*)&sA[n0 * NPG + 4 * m4];
            float4 a1 = *(const float4*)&sA[n1 * NPG + 4 * m4];
            float4 b0 = sb4[(4*m4+0)*5 + lq];
            float4 b1 = sb4[(4*m4+1)*5 + lq];
            float4 b2v = sb4[(4*m4+2)*5 + lq];
            float4 b3v = sb4[(4*m4+3)*5 + lq];
            FMA4(acc0, a0.x, b0); FMA4(acc0, a0.y, b1);
            FMA4(acc0, a0.z, b2v); FMA4(acc0, a0.w, b3v);
            FMA4(acc1, a1.x, b0); FMA4(acc1, a1.y, b1);
            FMA4(acc1, a1.z, b2v); FMA4(acc1, a1.w, b3v);
        }
        ((float4*)(sAS + n0 * K1))[lq] = acc0;
        ((float4*)(sAS + n1 * K1))[lq] = acc1;
    } else if (tid >= 128 && tid < 178) {
        int oo = tid - 128;
        int kp = oo / 5, lq = oo - kp * 5;
        int k0 = 2 * kp, k1 = k0 + 1;
        float4 acc0 = {0.f,0.f,0.f,0.f}, acc1 = {0.f,0.f,0.f,0.f};
#pragma unroll 8
        for (int n = 0; n < NPG; n++) {
            float2 s2v = *(const float2*)&sS[n * K1 + k0];
            float4 bv = ((const float4*)(sS + n * K1))[lq];
            FMA4(acc0, s2v.x, bv); FMA4(acc1, s2v.y, bv);
        }
        ((float4*)(sSS + k0 * K1))[lq] = acc0;
        ((float4*)(sSS + k1 * K1))[lq] = acc1;
    }
    __syncthreads();

    // ---- p7: A2 4-k (wave0) ; X2 4-k (wave1) ; den1 (wave2, f4) ----
    if (tid < 25) {
        int kp = tid / 5, lq = tid - kp * 5;
        int k0 = 4 * kp;
        float4 acc0 = {0.f,0.f,0.f,0.f}, acc1 = {0.f,0.f,0.f,0.f};
        float4 acc2 = {0.f,0.f,0.f,0.f}, acc3 = {0.f,0.f,0.f,0.f};
#pragma unroll 8
        for (int n = 0; n < NPG; n++) {
            float4 sv = *(const float4*)&sS[n * K1 + k0];
            float4 bv = ((const float4*)(sAS + n * K1))[lq];
            FMA4(acc0, sv.x, bv); FMA4(acc1, sv.y, bv);
            FMA4(acc2, sv.z, bv); FMA4(acc3, sv.w, bv);
        }
        ((float4*)(sA2 + (k0+0) * K1))[lq] = acc0;
        ((float4*)(sA2 + (k0+1) * K1))[lq] = acc1;
        ((float4*)(sA2 + (k0+2) * K1))[lq] = acc2;
        ((float4*)(sA2 + (k0+3) * K1))[lq] = acc3;
    } else if (tid >= 64 && tid < 104) {
        int oo = tid - 64;
        int kp = oo >> 3, fq = oo & 7;
        int k0 = 4 * kp;
        float4 acc0 = {0.f,0.f,0.f,0.f}, acc1 = {0.f,0.f,0.f,0.f};
        float4 acc2 = {0.f,0.f,0.f,0.f}, acc3 = {0.f,0.f,0.f,0.f};
#pragma unroll 8
        for (int n = 0; n < NPG; n++) {
            float4 sv = *(const float4*)&sS[n * K1 + k0];
            float4 bv = ((const float4*)(sXd + n * SH))[fq];
            FMA4(acc0, sv.x, bv); FMA4(acc1, sv.y, bv);
            FMA4(acc2, sv.z, bv); FMA4(acc3, sv.w, bv);
        }
        ((float4*)(sX2 + (k0+0) * SH))[fq] = acc0;
        ((float4*)(sX2 + (k0+1) * SH))[fq] = acc1;
        ((float4*)(sX2 + (k0+2) * SH))[fq] = acc2;
        ((float4*)(sX2 + (k0+3) * SH))[fq] = acc3;
    } else if (tid >= 128 && tid < 168) {
        int n = tid - 128;
        float s2 = 0.f;
#pragma unroll
        for (int j = 0; j < 5; j++) {
            float4 v = ((const float4*)(sS + n * K1))[j];
            s2 = fmaf(v.x, v.x, s2); s2 = fmaf(v.y, v.y, s2);
            s2 = fmaf(v.z, v.z, s2); s2 = fmaf(v.w, v.w, s2);
        }
        sden[n] = srowsA[n] * s2;
    }
    __syncthreads();

    // ---- p8: stats (waves 0-2) + XW2r/XW2o matmuls (f4 X2 reads) ----
    if (wid == 0) {              // closed-form ortho1 from SS
        float f = 0.f, tr = 0.f;
        for (int i = lane; i < K1 * K1; i += 64) {
            float t = sSS[i];
            f = fmaf(t, t, f);
            if (i % (K1 + 1) == 0) tr += t;
        }
        f = wave_red(f); tr = wave_red(tr);
        if (lane == 0)
            sc[2] = sqrtf(fmaxf(2.f - 2.f * tr / (sqrtf(f) * 4.47213595499958f), 0.f));
    } else if (wid == 1) {       // num1 = trace(A2) ; rownorm1 (A2 kept raw)
        float v = 0.f;
        if (lane < K1) {
            float s = 0.f;
#pragma unroll
            for (int j = 0; j < 5; j++) {
                float4 a = *(const float4*)&sA2[lane * K1 + 4*j];
                s += a.x + a.y + a.z + a.w;
            }
            float d = sA2[lane * (K1 + 1)];
            srowm[lane] = 1.f / (sqrtf(s - d) + EPSF);
            v = d;
        }
        v = wave_red(v);
        if (lane == 0) sc[0] = v;
    } else if (wid == 2) {       // den1
        float v = (lane < NPG) ? sden[lane] : 0.f;
        v = wave_red(v);
        if (lane == 0) sc[1] = v;
    }
    for (int o = tid; o < 320; o += NT) {
        int first = o < 160; int m = first ? o : o - 160;
        int n = m >> 3, fq = m & 7;
        const float4* wg = (const float4*)(first ? w2r_ : w2o_);
        float4 acc = {0.f,0.f,0.f,0.f};
#pragma unroll
        for (int j = 0; j < 8; j++) {
            float4 a = ((const float4*)(sX2 + n * SH))[j];
            float4 w0 = wg[(4*j+0) * 8 + fq];
            float4 w1 = wg[(4*j+1) * 8 + fq];
            float4 w2 = wg[(4*j+2) * 8 + fq];
            float4 w3 = wg[(4*j+3) * 8 + fq];
            FMA4(acc, a.x, w0); FMA4(acc, a.y, w1);
            FMA4(acc, a.z, w2); FMA4(acc, a.w, w3);
        }
        ((float4*)((first ? sXw2r : sXw2o) + n * SH))[fq] = acc;
    }
    __syncthreads();

    // ---- pC: X2' = relu(adj1n @ XW2r + XW2o + b2)  [f4 A2/srowm, diag-sub] --
    if (tid < 160) {
        int k = tid >> 3, fq = tid & 7;
        float4 a[5];
#pragma unroll
        for (int j = 0; j < 5; j++) {
            float4 av = *(const float4*)&sA2[k * K1 + 4*j];
            float4 rm = *(const float4*)&srowm[4*j];
            a[j].x = av.x * rm.x; a[j].y = av.y * rm.y;
            a[j].z = av.z * rm.z; a[j].w = av.w * rm.w;
        }
        float4 acc = {0.f,0.f,0.f,0.f};
#pragma unroll
        for (int j = 0; j < 5; j++) {
            float4 w0 = ((const float4*)(sXw2r + (4*j+0) * SH))[fq];
            float4 w1 = ((const float4*)(sXw2r + (4*j+1) * SH))[fq];
            float4 w2 = ((const float4*)(sXw2r + (4*j+2) * SH))[fq];
            float4 w3 = ((const float4*)(sXw2r + (4*j+3) * SH))[fq];
            FMA4(acc, a[j].x, w0); FMA4(acc, a[j].y, w1);
            FMA4(acc, a[j].z, w2); FMA4(acc, a[j].w, w3);
        }
        float adiag = sA2[k * (K1 + 1)] * srowm[k];
        float4 wk = ((const float4*)(sXw2r + k * SH))[fq];
        acc.x -= adiag * wk.x; acc.y -= adiag * wk.y;
        acc.z -= adiag * wk.z; acc.w -= adiag * wk.w;
        float4 bb = ((const float4*)b2_)[fq];
        float4 oo = ((const float4*)(sXw2o + k * SH))[fq];
        float rk = srowm[k];
        float4 r;
        r.x = fmaxf(fmaf(rk, acc.x, oo.x + bb.x), 0.f);
        r.y = fmaxf(fmaf(rk, acc.y, oo.y + bb.y), 0.f);
        r.z = fmaxf(fmaf(rk, acc.z, oo.z + bb.z), 0.f);
        r.w = fmaxf(fmaf(rk, acc.w, oo.w + bb.w), 0.f);
        ((float4*)(sX2 + k * SH))[fq] = r;
    }
    __syncthreads();

    // ---- p11: S2 logits + softmax2 fused (f4 reads, f2 writes) ----
    if (tid < K1) {
        float acc[K2];
#pragma unroll
        for (int q = 0; q < K2; q++) acc[q] = b_p2[q];
#pragma unroll
        for (int j = 0; j < 8; j++) {
            float4 a = ((const float4*)(sX2 + tid * SH))[j];
#pragma unroll
            for (int q = 0; q < K2; q++) acc[q] = fmaf(a.x, w_p2[(4*j+0) * K2 + q], acc[q]);
#pragma unroll
            for (int q = 0; q < K2; q++) acc[q] = fmaf(a.y, w_p2[(4*j+1) * K2 + q], acc[q]);
#pragma unroll
            for (int q = 0; q < K2; q++) acc[q] = fmaf(a.z, w_p2[(4*j+2) * K2 + q], acc[q]);
#pragma unroll
            for (int q = 0; q < K2; q++) acc[q] = fmaf(a.w, w_p2[(4*j+3) * K2 + q], acc[q]);
        }
        float m = -3.0e38f;
#pragma unroll
        for (int q = 0; q < K2; q++) m = fmaxf(m, acc[q]);
        float ssum = 0.f;
#pragma unroll
        for (int q = 0; q < K2; q++) { acc[q] = __expf(acc[q] - m); ssum += acc[q]; }
        float inv = 1.f / ssum;
#pragma unroll
        for (int q2 = 0; q2 < 5; q2++) {
            float2 wv; wv.x = acc[2*q2] * inv; wv.y = acc[2*q2+1] * inv;
            *(float2*)&sS2[tid * K2 + 2*q2] = wv;
        }
    }
    __syncthreads();

    // ---- p12: AS2 (waves 0-1) ; SS2+den2 (wave 2) ; X3 (wave 3) ----
    if (tid < 100) {             // AS2: (n, l-pair), f4 A2/srowm + f2 S2
        int n = tid / 5, lp = tid - (tid / 5) * 5;
        int l0 = 2 * lp;
        float accx = 0.f, accy = 0.f;
#pragma unroll
        for (int j = 0; j < 5; j++) {
            float4 av = *(const float4*)&sA2[n * K1 + 4*j];
            float4 rm = *(const float4*)&srowm[4*j];
            float2 s0 = *(const float2*)&sS2[(4*j+0) * K2 + l0];
            float2 s1 = *(const float2*)&sS2[(4*j+1) * K2 + l0];
            float2 s2v = *(const float2*)&sS2[(4*j+2) * K2 + l0];
            float2 s3 = *(const float2*)&sS2[(4*j+3) * K2 + l0];
            float c0 = av.x * rm.x, c1 = av.y * rm.y, c2 = av.z * rm.z, c3 = av.w * rm.w;
            accx = fmaf(c0, s0.x, accx); accy = fmaf(c0, s0.y, accy);
            accx = fmaf(c1, s1.x, accx); accy = fmaf(c1, s1.y, accy);
            accx = fmaf(c2, s2v.x, accx); accy = fmaf(c2, s2v.y, accy);
            accx = fmaf(c3, s3.x, accx); accy = fmaf(c3, s3.y, accy);
        }
        float cd = sA2[n * (K1 + 1)] * srowm[n];
        float2 sn = *(const float2*)&sS2[n * K2 + l0];
        accx -= cd * sn.x; accy -= cd * sn.y;
        float rn = srowm[n];
        float2 wv; wv.x = accx * rn; wv.y = accy * rn;
        *(float2*)&sAS2[n * K2 + l0] = wv;
    } else if (tid >= 128 && tid < 153) {   // SS2: (k-pair, l-pair)
        int oo = tid - 128;
        int kp = oo / 5, lp = oo - kp * 5;
        int k0 = 2 * kp, l0 = 2 * lp;
        float a00 = 0.f, a01 = 0.f, a10 = 0.f, a11 = 0.f;
#pragma unroll
        for (int n = 0; n < K1; n++) {
            float2 a = *(const float2*)&sS2[n * K2 + k0];
            float2 b = *(const float2*)&sS2[n * K2 + l0];
            a00 = fmaf(a.x, b.x, a00); a01 = fmaf(a.x, b.y, a01);
            a10 = fmaf(a.y, b.x, a10); a11 = fmaf(a.y, b.y, a11);
        }
        sSS[(k0+0) * K2 + l0]     = a00;
        sSS[(k0+0) * K2 + l0 + 1] = a01;
        sSS[(k0+1) * K2 + l0]     = a10;
        sSS[(k0+1) * K2 + l0 + 1] = a11;
    } else if (tid >= 160 && tid < 180) {   // den2 terms
        int n = tid - 160;
        float da = 0.f;
#pragma unroll
        for (int j = 0; j < 5; j++) {
            float4 av = *(const float4*)&sA2[n * K1 + 4*j];
            float4 rm = *(const float4*)&srowm[4*j];
            da = fmaf(av.x, rm.x, da); da = fmaf(av.y, rm.y, da);
            da = fmaf(av.z, rm.z, da); da = fmaf(av.w, rm.w, da);
        }
        da -= sA2[n * (K1 + 1)] * srowm[n];
        da *= srowm[n];
        float s2 = 0.f;
#pragma unroll
        for (int q2 = 0; q2 < 5; q2++) {
            float2 v = *(const float2*)&sS2[n * K2 + 2*q2];
            s2 = fmaf(v.x, v.x, s2); s2 = fmaf(v.y, v.y, s2);
        }
        sden[n] = da * s2;
    } else if (tid >= 192 && tid < 232) {   // X3 = S2^T X2' (2-k tiles)
        int oo = tid - 192;
        int kp = oo >> 3, fq = oo & 7;
        int k0 = 2 * kp;
        float4 acc0 = {0.f,0.f,0.f,0.f}, acc1 = {0.f,0.f,0.f,0.f};
#pragma unroll
        for (int n = 0; n < K1; n++) {
            float2 sv = *(const float2*)&sS2[n * K2 + k0];
            float4 bv = ((const float4*)(sX2 + n * SH))[fq];
            FMA4(acc0, sv.x, bv); FMA4(acc1, sv.y, bv);
        }
        ((float4*)(sX3 + (k0+0) * SH))[fq] = acc0;
        ((float4*)(sX3 + (k0+1) * SH))[fq] = acc1;
    }
    __syncthreads();

    // ---- p13: A3 = S2^T AS2 f2-tiled (wave0) ; den2 (w2) ; ortho2 (w3) ----
    if (tid < 25) {
        int kp = tid / 5, lp = tid - kp * 5;
        int k0 = 2 * kp, l0 = 2 * lp;
        float a00 = 0.f, a01 = 0.f, a10 = 0.f, a11 = 0.f;
#pragma unroll
        for (int n = 0; n < K1; n++) {
            float2 sv = *(const float2*)&sS2[n * K2 + k0];
            float2 av = *(const float2*)&sAS2[n * K2 + l0];
            a00 = fmaf(sv.x, av.x, a00); a01 = fmaf(sv.x, av.y, a01);
            a10 = fmaf(sv.y, av.x, a10); a11 = fmaf(sv.y, av.y, a11);
        }
        sA3[(k0+0) * K2 + l0]     = a00;
        sA3[(k0+0) * K2 + l0 + 1] = a01;
        sA3[(k0+1) * K2 + l0]     = a10;
        sA3[(k0+1) * K2 + l0 + 1] = a11;
    } else if (wid == 2) {
        float v = (lane < K1) ? sden[lane] : 0.f;
        v = wave_red(v);
        if (lane == 0) sc[5] = v;
    } else if (wid == 3) {
        float f = 0.f, tr = 0.f;
        for (int i = lane; i < K2 * K2; i += 64) {
            float t = sSS[i];
            f = fmaf(t, t, f);
            if (i % (K2 + 1) == 0) tr += t;
        }
        f = wave_red(f); tr = wave_red(tr);
        if (lane == 0)
            sc[6] = sqrtf(fmaxf(2.f - 2.f * tr / (sqrtf(f) * 3.1622776601683795f), 0.f));
    }
    __syncthreads();

    // ---- p14: XW3r/XW3o (f4 X3 reads) ; rownorm2 + loss (wave 3) ----
    if (tid < 160) {
        bool first = (tid < 80);
        int oo = first ? tid : tid - 80;
        int n = oo >> 3, fq = oo & 7;
        const float4* wg = (const float4*)(first ? w3r_ : w3o_);
        float4 acc = {0.f,0.f,0.f,0.f};
#pragma unroll
        for (int j = 0; j < 8; j++) {
            float4 a = ((const float4*)(sX3 + n * SH))[j];
            float4 w0 = wg[(4*j+0) * 8 + fq];
            float4 w1 = wg[(4*j+1) * 8 + fq];
            float4 w2 = wg[(4*j+2) * 8 + fq];
            float4 w3 = wg[(4*j+3) * 8 + fq];
            FMA4(acc, a.x, w0); FMA4(acc, a.y, w1);
            FMA4(acc, a.z, w2); FMA4(acc, a.w, w3);
        }
        if (first) ((float4*)(sW3r + n * SH))[fq] = acc;
        else       ((float4*)(sW3o + n * SH))[fq] = acc;
    } else if (tid >= 192 && tid < 202) {
        int l = tid - 192;
        float s = 0.f;
#pragma unroll
        for (int j = 0; j < 5; j++) {
            float2 a = *(const float2*)&sA3[l * K2 + 2*j];
            s += a.x + a.y;
        }
        s -= sA3[l * (K2 + 1)];
        srowm[l] = 1.f / (sqrtf(s) + EPSF);
    } else if (tid == 202) {
        float num2 = 0.f;
#pragma unroll
        for (int k = 0; k < K2; k++) num2 += sA3[k * (K2 + 1)];
        wsg[g] = -(sc[0] / sc[1]) + sc[2] - num2 / sc[5] + sc[6];
    }
    __syncthreads();

    // ---- p15: X4 = adj2n @ XW3r + XW3o + b3  [f2 A3/srowm, diag-sub] ----
    if (tid < 80) {
        int k = tid >> 3, fq = tid & 7;
        float4 acc = {0.f,0.f,0.f,0.f};
#pragma unroll
        for (int j = 0; j < 5; j++) {
            float2 av = *(const float2*)&sA3[k * K2 + 2*j];
            float2 rm = *(const float2*)&srowm[2*j];
            float c0 = av.x * rm.x, c1 = av.y * rm.y;
            float4 w0 = ((const float4*)(sW3r + (2*j+0) * SH))[fq];
            float4 w1 = ((const float4*)(sW3r + (2*j+1) * SH))[fq];
            FMA4(acc, c0, w0); FMA4(acc, c1, w1);
        }
        float adiag = sA3[k * (K2 + 1)] * srowm[k];
        float4 wk = ((const float4*)(sW3r + k * SH))[fq];
        acc.x -= adiag * wk.x; acc.y -= adiag * wk.y;
        acc.z -= adiag * wk.z; acc.w -= adiag * wk.w;
        float4 bb = ((const float4*)b3_)[fq];
        float4 oo = ((const float4*)(sW3o + k * SH))[fq];
        float rk = srowm[k];
        float4 r;
        r.x = fmaf(rk, acc.x, oo.x + bb.x);
        r.y = fmaf(rk, acc.y, oo.y + bb.y);
        r.z = fmaf(rk, acc.z, oo.z + bb.z);
        r.w = fmaf(rk, acc.w, oo.w + bb.w);
        ((float4*)(sX4 + k * SH))[fq] = r;
    }
    __syncthreads();

    // ---- p16: mean pool + MLP head (wave 0, shuffle-based) ----
    if (wid == 0) {
        int f = lane & 31;
        float pool = 0.f;
#pragma unroll
        for (int n = 0; n < K2; n++) pool += sX4[n * SH + f];
        pool *= (1.f / K2);
        float acc = b_l1[f];
#pragma unroll
        for (int j = 0; j < HID; j++)
            acc = fmaf(__shfl(pool, j, 64), w_l1[j * HID + f], acc);
        float t1 = fmaxf(acc, 0.f);
        int o = (lane < OUTC) ? lane : 0;
        float acc2 = b_l2[o];
#pragma unroll
        for (int j = 0; j < HID; j++)
            acc2 = fmaf(__shfl(t1, j, 64), w_l2[j * OUTC + o], acc2);
        if (lane < OUTC) out[(size_t)g * OUTC + lane] = acc2;
    }
}

__global__ void loss_reduce(const float* __restrict__ wsg, float* __restrict__ out)
{
    __shared__ float sred[4];
    int tid = threadIdx.x;
    float s = 0.f;
    for (int i = tid; i < Bg; i += NT) s += wsg[i];
    s = wave_red(s);
    if ((tid & 63) == 0) sred[tid >> 6] = s;
    __syncthreads();
    if (tid == 0) out[(size_t)Bg * OUTC] = (sred[0] + sred[1] + sred[2] + sred[3]) * (1.f / Bg);
}

extern "C" void kernel_launch(void* const* d_in, const int* in_sizes, int n_in,
                              void* d_out, int out_size, void* d_ws, size_t ws_size,
                              hipStream_t stream)
{
    const float* x    = (const float*)d_in[0];
    const int*   ei   = (const int*)  d_in[1];
    // d_in[2] = batch (unused: graphs are contiguous blocks of NPG nodes)
    const float* w_c1 = (const float*)d_in[3];
    const float* b_c1 = (const float*)d_in[4];
    const float* w_p1 = (const float*)d_in[5];
    const float* b_p1 = (const float*)d_in[6];
    const float* w2r  = (const float*)d_in[7];
    const float* b2   = (const float*)d_in[8];
    const float* w2o  = (const float*)d_in[9];
    const float* w_p2 = (const float*)d_in[10];
    const float* b_p2 = (const float*)d_in[11];
    const float* w3r  = (const float*)d_in[12];
    const float* b3   = (const float*)d_in[13];
    const float* w3o  = (const float*)d_in[14];
    const float* w_l1 = (const float*)d_in[15];
    const float* b_l1 = (const float*)d_in[16];
    const float* w_l2 = (const float*)d_in[17];
    const float* b_l2 = (const float*)d_in[18];
    float* out = (float*)d_out;
    float* wsg = (float*)d_ws;

    hipLaunchKernelGGL(mincut_fused, dim3(Bg), dim3(NT), 0, stream,
                       x, ei, w_c1, b_c1, w_p1, b_p1, w2r, b2, w2o,
                       w_p2, b_p2, w3r, b3, w3o, w_l1, b_l1, w_l2, b_l2,
                       out, wsg);
    hipLaunchKernelGGL(loss_reduce, dim3(1), dim3(NT), 0, stream, wsg, out);
}

// Round 18
// 232.192 us; speedup vs baseline: 1.1316x; 1.0050x over previous
//
#include <hip/hip_runtime.h>

#define NT 256

constexpr int Bg   = 8192;      // graphs
constexpr int NPG  = 40;
constexpr int EPG  = 640;
constexpr int IN_  = 64;
constexpr int HID  = 32;
constexpr int K1   = 20;
constexpr int K2   = 10;
constexpr int OUTC = 10;
constexpr int NE   = Bg * NPG * 16;
constexpr int SH   = 36;        // padded 32-wide row stride
constexpr float EPSF = 1e-15f;

#define FMA4(acc, a, b) do { \
    float _s = (a); \
    acc.x = fmaf(_s, (b).x, acc.x); \
    acc.y = fmaf(_s, (b).y, acc.y); \
    acc.z = fmaf(_s, (b).z, acc.z); \
    acc.w = fmaf(_s, (b).w, acc.w); } while (0)

__device__ __forceinline__ float wave_red(float v) {
#pragma unroll
    for (int off = 32; off > 0; off >>= 1) v += __shfl_down(v, off, 64);
    return v;
}

// r18 = r17 (233us stable best) + one overlap fix: since r12 removed
// X-staging, sB's H region is DEAD during p1 — so H is written directly in
// p1 (DS writes overlap the global-X load latency; hacc no longer lives
// across a barrier -> lower VGPR). p1b is degrees-only (wave 3).
// LDS overlay (~20.9 KB); f4/f2 vectorized LDS reads; 4-wide register tiles
// in p3/p7; diag via full-sum+subtract; wave-aligned task partitions.
// BUG history: r9 sSS[oo-200]; r13 p6 AS half-coverage; r16 atomic-counter
// contention + serialized p4 fusion — all avoided here.
// NOTE: __launch_bounds__(256,4) — (256,6) forced 40 VGPR + 38KB spill (r4).
__global__ __launch_bounds__(NT, 4)
void mincut_fused(const float* __restrict__ x, const int* __restrict__ ei,
                  const float* __restrict__ w_c1, const float* __restrict__ b_c1,
                  const float* __restrict__ w_p1, const float* __restrict__ b_p1,
                  const float* __restrict__ w2r_, const float* __restrict__ b2_,
                  const float* __restrict__ w2o_,
                  const float* __restrict__ w_p2, const float* __restrict__ b_p2,
                  const float* __restrict__ w3r_, const float* __restrict__ b3_,
                  const float* __restrict__ w3o_,
                  const float* __restrict__ w_l1, const float* __restrict__ b_l1,
                  const float* __restrict__ w_l2, const float* __restrict__ b_l2,
                  float* __restrict__ out, float* __restrict__ wsg)
{
    __shared__ __align__(16) float sA[NPG * NPG];    // 1600
    __shared__ __align__(16) float sB[2000];
    __shared__ __align__(16) float sXd[NPG * SH];    // 1440
    __shared__ __align__(16) float sdinv[NPG];
    __shared__ __align__(16) float srowsA[NPG];
    __shared__ __align__(16) float srowm[NPG];
    __shared__ __align__(16) float sden[NPG];
    __shared__ __align__(16) float sc[8];
    // sc: [0]num1 [1]den1 [2]o1 [5]den2 [6]o2

    float* sA2  = sA;            // 20x20 raw
    float* sX2  = sA + 400;      // 20xSH  (p7-p12)
    float* sA3  = sA + 400;      // 10x10 raw (p13+, X2 dead)
    float* sH   = sB;            // 40xSH
    float* sS   = sB;            // 40x20
    float* sAS  = sB + 800;      // 40x20
    float* sS2  = sB + 800;      // 20x10
    float* sAS2 = sB + 1000;     // 20x10
    float* sX3  = sB + 1200;     // 10xSH
    float* sX4  = sB + 1200;     // 10xSH (after X3 dead)
    float* sSS  = sB + 1600;     // 400 (SS then SS2)
    float* sXw2r= sXd;           // 20xSH
    float* sXw2o= sXd + 720;     // 20xSH
    float* sW3r = sXd;           // 10xSH
    float* sW3o = sXd + 360;     // 10xSH

    const int g    = blockIdx.x;
    const int tid  = threadIdx.x;
    const int lane = tid & 63;
    const int wid  = tid >> 6;

    // ---- p0: edges -> regs, zero A ----
    int er0, ec0, er1, ec1, er2 = -1, ec2 = 0;
    {
        const int eb = g * EPG, nb = g * NPG;
        int e = eb + tid;
        er0 = ei[e] - nb; ec0 = ei[NE + e] - nb;
        e += NT;
        er1 = ei[e] - nb; ec1 = ei[NE + e] - nb;
        if (tid + 2 * NT < EPG) {
            e += NT;
            er2 = ei[e] - nb; ec2 = ei[NE + e] - nb;
        }
    }
    for (int i = tid; i < NPG * NPG; i += NT) sA[i] = 0.f;
    __syncthreads();

    // ---- p1: adj scatter + H = X @ W1, written DIRECTLY (sB dead here) ----
    atomicAdd(&sA[er0 * NPG + ec0], 1.f);
    atomicAdd(&sA[er1 * NPG + ec1], 1.f);
    if (er2 >= 0) atomicAdd(&sA[er2 * NPG + ec2], 1.f);

    if (tid < 160) {
        int np = tid >> 3, fq = tid & 7;
        int n0 = 2 * np, n1 = n0 + 1;
        const float4* x0 = (const float4*)(x + (size_t)g * (NPG * IN_) + n0 * IN_);
        const float4* x1 = (const float4*)(x + (size_t)g * (NPG * IN_) + n1 * IN_);
        const float4* wg = (const float4*)w_c1;
        float4 hacc0 = {0.f,0.f,0.f,0.f}, hacc1 = {0.f,0.f,0.f,0.f};
#pragma unroll 4
        for (int kk = 0; kk < IN_ / 4; kk++) {
            float4 a0 = x0[kk], a1 = x1[kk];
            float4 w0 = wg[(4*kk+0)*8 + fq];
            float4 w1 = wg[(4*kk+1)*8 + fq];
            float4 w2 = wg[(4*kk+2)*8 + fq];
            float4 w3 = wg[(4*kk+3)*8 + fq];
            FMA4(hacc0, a0.x, w0); FMA4(hacc0, a0.y, w1);
            FMA4(hacc0, a0.z, w2); FMA4(hacc0, a0.w, w3);
            FMA4(hacc1, a1.x, w0); FMA4(hacc1, a1.y, w1);
            FMA4(hacc1, a1.z, w2); FMA4(hacc1, a1.w, w3);
        }
        ((float4*)(sH + n0 * SH))[fq] = hacc0;
        ((float4*)(sH + n1 * SH))[fq] = hacc1;
    }
    __syncthreads();

    // ---- p1b: degrees only (wave 3, f4 reads) ----
    if (tid >= 192 && tid < 202) {             // col sums -> dinv (4 cols each)
        int c0 = 4 * (tid - 192);
        float4 s = {0.f,0.f,0.f,0.f};
#pragma unroll 8
        for (int r = 0; r < NPG; r++) {
            float4 a = *(const float4*)&sA[r * NPG + c0];
            s.x += a.x; s.y += a.y; s.z += a.z; s.w += a.w;
        }
        sdinv[c0+0] = rsqrtf(s.x + 1.f);
        sdinv[c0+1] = rsqrtf(s.y + 1.f);
        sdinv[c0+2] = rsqrtf(s.z + 1.f);
        sdinv[c0+3] = rsqrtf(s.w + 1.f);
    } else if (tid >= 202 && tid < 212) {      // row sums (4 rows each)
        int r0 = 4 * (tid - 202);
        float s0 = 0.f, s1 = 0.f, s2 = 0.f, s3 = 0.f;
#pragma unroll
        for (int j = 0; j < 10; j++) {
            float4 a0 = *(const float4*)&sA[(r0+0) * NPG + 4*j];
            float4 a1 = *(const float4*)&sA[(r0+1) * NPG + 4*j];
            float4 a2 = *(const float4*)&sA[(r0+2) * NPG + 4*j];
            float4 a3 = *(const float4*)&sA[(r0+3) * NPG + 4*j];
            s0 += a0.x + a0.y + a0.z + a0.w;
            s1 += a1.x + a1.y + a1.z + a1.w;
            s2 += a2.x + a2.y + a2.z + a2.w;
            s3 += a3.x + a3.y + a3.z + a3.w;
        }
        srowsA[r0+0] = s0; srowsA[r0+1] = s1;
        srowsA[r0+2] = s2; srowsA[r0+3] = s3;
    }
    __syncthreads();

    // ---- p3: Xd = relu(D^-1/2 (A+I) D^-1/2 H + b1)  [4-col tiles, f4 A] ----
    if (tid < 80) {
        int cp = tid >> 3, fq = tid & 7;
        int c0 = 4 * cp;
        float4 acc0 = {0.f,0.f,0.f,0.f}, acc1 = {0.f,0.f,0.f,0.f};
        float4 acc2 = {0.f,0.f,0.f,0.f}, acc3 = {0.f,0.f,0.f,0.f};
#pragma unroll 8
        for (int r = 0; r < NPG; r++) {
            float4 a = *(const float4*)&sA[r * NPG + c0];
            float dv = sdinv[r];
            float4 bv = ((const float4*)(sH + r * SH))[fq];
            FMA4(acc0, a.x * dv, bv);
            FMA4(acc1, a.y * dv, bv);
            FMA4(acc2, a.z * dv, bv);
            FMA4(acc3, a.w * dv, bv);
        }
        float4 bb = ((const float4*)b_c1)[fq];
#pragma unroll
        for (int i = 0; i < 4; i++) {
            float4 acc = (i == 0) ? acc0 : (i == 1) ? acc1 : (i == 2) ? acc2 : acc3;
            int c = c0 + i;
            float d = sdinv[c];
            float4 h = ((const float4*)(sH + c * SH))[fq];
            float4 r;
            r.x = fmaxf(fmaf(d, fmaf(d, h.x, acc.x), bb.x), 0.f);
            r.y = fmaxf(fmaf(d, fmaf(d, h.y, acc.y), bb.y), 0.f);
            r.z = fmaxf(fmaf(d, fmaf(d, h.z, acc.z), bb.z), 0.f);
            r.w = fmaxf(fmaf(d, fmaf(d, h.w, acc.w), bb.w), 0.f);
            ((float4*)(sXd + c * SH))[fq] = r;
        }
    }
    __syncthreads();

    // ---- p4: S1 logits = Xd @ Wp1 + bp1  (f4 Xd reads) ----
    if (tid < 100) {
        int np = tid / 5, lq = tid - np * 5;
        int n0 = 2 * np, n1 = n0 + 1;
        const float4* wg = (const float4*)w_p1;
        float4 bb = ((const float4*)b_p1)[lq];
        float4 acc0 = bb, acc1 = bb;
#pragma unroll
        for (int j = 0; j < 8; j++) {
            float4 a0 = ((const float4*)(sXd + n0 * SH))[j];
            float4 a1 = ((const float4*)(sXd + n1 * SH))[j];
            float4 w0 = wg[(4*j+0) * 5 + lq];
            float4 w1 = wg[(4*j+1) * 5 + lq];
            float4 w2 = wg[(4*j+2) * 5 + lq];
            float4 w3 = wg[(4*j+3) * 5 + lq];
            FMA4(acc0, a0.x, w0); FMA4(acc0, a0.y, w1);
            FMA4(acc0, a0.z, w2); FMA4(acc0, a0.w, w3);
            FMA4(acc1, a1.x, w0); FMA4(acc1, a1.y, w1);
            FMA4(acc1, a1.z, w2); FMA4(acc1, a1.w, w3);
        }
        ((float4*)(sS + n0 * K1))[lq] = acc0;
        ((float4*)(sS + n1 * K1))[lq] = acc1;
    }
    __syncthreads();

    // ---- p5: softmax1 (f4 row I/O) ----
    if (tid < NPG) {
        float4* row4 = (float4*)(sS + tid * K1);
        float4 v[5];
        float m = -3.0e38f;
#pragma unroll
        for (int j = 0; j < 5; j++) {
            v[j] = row4[j];
            m = fmaxf(m, fmaxf(fmaxf(v[j].x, v[j].y), fmaxf(v[j].z, v[j].w)));
        }
        float ssum = 0.f;
#pragma unroll
        for (int j = 0; j < 5; j++) {
            v[j].x = __expf(v[j].x - m); v[j].y = __expf(v[j].y - m);
            v[j].z = __expf(v[j].z - m); v[j].w = __expf(v[j].w - m);
            ssum += v[j].x + v[j].y + v[j].z + v[j].w;
        }
        float inv = 1.f / ssum;
#pragma unroll
        for (int j = 0; j < 5; j++) {
            v[j].x *= inv; v[j].y *= inv; v[j].z *= inv; v[j].w *= inv;
            row4[j] = v[j];
        }
    }
    __syncthreads();

    // ---- p6: AS = A @ S (waves 0-1, ALL 40 rows) ; SS = S^T S (wave 2) ----
    if (tid < 100) {
        int np = tid / 5, lq = tid - np * 5;
        int n0 = 2 * np, n1 = n0 + 1;
        const float4* sb4 = (const float4*)sS;
        float4 acc0 = {0.f,0.f,0.f,0.f}, acc1 = {0.f,0.f,0.f,0.f};
#pragma unroll
        for (int m4 = 0; m4 < NPG / 4; m4++) {
            float4 a0 = *(const float4*)&sA[n0 * NPG + 4 * m4];
            float4 a1 = *(const float4*)&sA[n1 * NPG + 4 * m4];
            float4 b0 = sb4[(4*m4+0)*5 + lq];
            float4 b1 = sb4[(4*m4+1)*5 + lq];
            float4 b2v = sb4[(4*m4+2)*5 + lq];
            float4 b3v = sb4[(4*m4+3)*5 + lq];
            FMA4(acc0, a0.x, b0); FMA4(acc0, a0.y, b1);
            FMA4(acc0, a0.z, b2v); FMA4(acc0, a0.w, b3v);
            FMA4(acc1, a1.x, b0); FMA4(acc1, a1.y, b1);
            FMA4(acc1, a1.z, b2v); FMA4(acc1, a1.w, b3v);
        }
        ((float4*)(sAS + n0 * K1))[lq] = acc0;
        ((float4*)(sAS + n1 * K1))[lq] = acc1;
    } else if (tid >= 128 && tid < 178) {
        int oo = tid - 128;
        int kp = oo / 5, lq = oo - kp * 5;
        int k0 = 2 * kp, k1 = k0 + 1;
        float4 acc0 = {0.f,0.f,0.f,0.f}, acc1 = {0.f,0.f,0.f,0.f};
#pragma unroll 8
        for (int n = 0; n < NPG; n++) {
            float2 s2v = *(const float2*)&sS[n * K1 + k0];
            float4 bv = ((const float4*)(sS + n * K1))[lq];
            FMA4(acc0, s2v.x, bv); FMA4(acc1, s2v.y, bv);
        }
        ((float4*)(sSS + k0 * K1))[lq] = acc0;
        ((float4*)(sSS + k1 * K1))[lq] = acc1;
    }
    __syncthreads();

    // ---- p7: A2 4-k (wave0) ; X2 4-k (wave1) ; den1 (wave2, f4) ----
    if (tid < 25) {
        int kp = tid / 5, lq = tid - kp * 5;
        int k0 = 4 * kp;
        float4 acc0 = {0.f,0.f,0.f,0.f}, acc1 = {0.f,0.f,0.f,0.f};
        float4 acc2 = {0.f,0.f,0.f,0.f}, acc3 = {0.f,0.f,0.f,0.f};
#pragma unroll 8
        for (int n = 0; n < NPG; n++) {
            float4 sv = *(const float4*)&sS[n * K1 + k0];
            float4 bv = ((const float4*)(sAS + n * K1))[lq];
            FMA4(acc0, sv.x, bv); FMA4(acc1, sv.y, bv);
            FMA4(acc2, sv.z, bv); FMA4(acc3, sv.w, bv);
        }
        ((float4*)(sA2 + (k0+0) * K1))[lq] = acc0;
        ((float4*)(sA2 + (k0+1) * K1))[lq] = acc1;
        ((float4*)(sA2 + (k0+2) * K1))[lq] = acc2;
        ((float4*)(sA2 + (k0+3) * K1))[lq] = acc3;
    } else if (tid >= 64 && tid < 104) {
        int oo = tid - 64;
        int kp = oo >> 3, fq = oo & 7;
        int k0 = 4 * kp;
        float4 acc0 = {0.f,0.f,0.f,0.f}, acc1 = {0.f,0.f,0.f,0.f};
        float4 acc2 = {0.f,0.f,0.f,0.f}, acc3 = {0.f,0.f,0.f,0.f};
#pragma unroll 8
        for (int n = 0; n < NPG; n++) {
            float4 sv = *(const float4*)&sS[n * K1 + k0];
            float4 bv = ((const float4*)(sXd + n * SH))[fq];
            FMA4(acc0, sv.x, bv); FMA4(acc1, sv.y, bv);
            FMA4(acc2, sv.z, bv); FMA4(acc3, sv.w, bv);
        }
        ((float4*)(sX2 + (k0+0) * SH))[fq] = acc0;
        ((float4*)(sX2 + (k0+1) * SH))[fq] = acc1;
        ((float4*)(sX2 + (k0+2) * SH))[fq] = acc2;
        ((float4*)(sX2 + (k0+3) * SH))[fq] = acc3;
    } else if (tid >= 128 && tid < 168) {
        int n = tid - 128;
        float s2 = 0.f;
#pragma unroll
        for (int j = 0; j < 5; j++) {
            float4 v = ((const float4*)(sS + n * K1))[j];
            s2 = fmaf(v.x, v.x, s2); s2 = fmaf(v.y, v.y, s2);
            s2 = fmaf(v.z, v.z, s2); s2 = fmaf(v.w, v.w, s2);
        }
        sden[n] = srowsA[n] * s2;
    }
    __syncthreads();

    // ---- p8: stats (waves 0-2) + XW2r/XW2o matmuls (f4 X2 reads) ----
    if (wid == 0) {              // closed-form ortho1 from SS
        float f = 0.f, tr = 0.f;
        for (int i = lane; i < K1 * K1; i += 64) {
            float t = sSS[i];
            f = fmaf(t, t, f);
            if (i % (K1 + 1) == 0) tr += t;
        }
        f = wave_red(f); tr = wave_red(tr);
        if (lane == 0)
            sc[2] = sqrtf(fmaxf(2.f - 2.f * tr / (sqrtf(f) * 4.47213595499958f), 0.f));
    } else if (wid == 1) {       // num1 = trace(A2) ; rownorm1 (A2 kept raw)
        float v = 0.f;
        if (lane < K1) {
            float s = 0.f;
#pragma unroll
            for (int j = 0; j < 5; j++) {
                float4 a = *(const float4*)&sA2[lane * K1 + 4*j];
                s += a.x + a.y + a.z + a.w;
            }
            float d = sA2[lane * (K1 + 1)];
            srowm[lane] = 1.f / (sqrtf(s - d) + EPSF);
            v = d;
        }
        v = wave_red(v);
        if (lane == 0) sc[0] = v;
    } else if (wid == 2) {       // den1
        float v = (lane < NPG) ? sden[lane] : 0.f;
        v = wave_red(v);
        if (lane == 0) sc[1] = v;
    }
    for (int o = tid; o < 320; o += NT) {
        int first = o < 160; int m = first ? o : o - 160;
        int n = m >> 3, fq = m & 7;
        const float4* wg = (const float4*)(first ? w2r_ : w2o_);
        float4 acc = {0.f,0.f,0.f,0.f};
#pragma unroll
        for (int j = 0; j < 8; j++) {
            float4 a = ((const float4*)(sX2 + n * SH))[j];
            float4 w0 = wg[(4*j+0) * 8 + fq];
            float4 w1 = wg[(4*j+1) * 8 + fq];
            float4 w2 = wg[(4*j+2) * 8 + fq];
            float4 w3 = wg[(4*j+3) * 8 + fq];
            FMA4(acc, a.x, w0); FMA4(acc, a.y, w1);
            FMA4(acc, a.z, w2); FMA4(acc, a.w, w3);
        }
        ((float4*)((first ? sXw2r : sXw2o) + n * SH))[fq] = acc;
    }
    __syncthreads();

    // ---- pC: X2' = relu(adj1n @ XW2r + XW2o + b2)  [f4 A2/srowm, diag-sub] --
    if (tid < 160) {
        int k = tid >> 3, fq = tid & 7;
        float4 a[5];
#pragma unroll
        for (int j = 0; j < 5; j++) {
            float4 av = *(const float4*)&sA2[k * K1 + 4*j];
            float4 rm = *(const float4*)&srowm[4*j];
            a[j].x = av.x * rm.x; a[j].y = av.y * rm.y;
            a[j].z = av.z * rm.z; a[j].w = av.w * rm.w;
        }
        float4 acc = {0.f,0.f,0.f,0.f};
#pragma unroll
        for (int j = 0; j < 5; j++) {
            float4 w0 = ((const float4*)(sXw2r + (4*j+0) * SH))[fq];
            float4 w1 = ((const float4*)(sXw2r + (4*j+1) * SH))[fq];
            float4 w2 = ((const float4*)(sXw2r + (4*j+2) * SH))[fq];
            float4 w3 = ((const float4*)(sXw2r + (4*j+3) * SH))[fq];
            FMA4(acc, a[j].x, w0); FMA4(acc, a[j].y, w1);
            FMA4(acc, a[j].z, w2); FMA4(acc, a[j].w, w3);
        }
        float adiag = sA2[k * (K1 + 1)] * srowm[k];
        float4 wk = ((const float4*)(sXw2r + k * SH))[fq];
        acc.x -= adiag * wk.x; acc.y -= adiag * wk.y;
        acc.z -= adiag * wk.z; acc.w -= adiag * wk.w;
        float4 bb = ((const float4*)b2_)[fq];
        float4 oo = ((const float4*)(sXw2o + k * SH))[fq];
        float rk = srowm[k];
        float4 r;
        r.x = fmaxf(fmaf(rk, acc.x, oo.x + bb.x), 0.f);
        r.y = fmaxf(fmaf(rk, acc.y, oo.y + bb.y), 0.f);
        r.z = fmaxf(fmaf(rk, acc.z, oo.z + bb.z), 0.f);
        r.w = fmaxf(fmaf(rk, acc.w, oo.w + bb.w), 0.f);
        ((float4*)(sX2 + k * SH))[fq] = r;
    }
    __syncthreads();

    // ---- p11: S2 logits + softmax2 fused (f4 reads, f2 writes) ----
    if (tid < K1) {
        float acc[K2];
#pragma unroll
        for (int q = 0; q < K2; q++) acc[q] = b_p2[q];
#pragma unroll
        for (int j = 0; j < 8; j++) {
            float4 a = ((const float4*)(sX2 + tid * SH))[j];
#pragma unroll
            for (int q = 0; q < K2; q++) acc[q] = fmaf(a.x, w_p2[(4*j+0) * K2 + q], acc[q]);
#pragma unroll
            for (int q = 0; q < K2; q++) acc[q] = fmaf(a.y, w_p2[(4*j+1) * K2 + q], acc[q]);
#pragma unroll
            for (int q = 0; q < K2; q++) acc[q] = fmaf(a.z, w_p2[(4*j+2) * K2 + q], acc[q]);
#pragma unroll
            for (int q = 0; q < K2; q++) acc[q] = fmaf(a.w, w_p2[(4*j+3) * K2 + q], acc[q]);
        }
        float m = -3.0e38f;
#pragma unroll
        for (int q = 0; q < K2; q++) m = fmaxf(m, acc[q]);
        float ssum = 0.f;
#pragma unroll
        for (int q = 0; q < K2; q++) { acc[q] = __expf(acc[q] - m); ssum += acc[q]; }
        float inv = 1.f / ssum;
#pragma unroll
        for (int q2 = 0; q2 < 5; q2++) {
            float2 wv; wv.x = acc[2*q2] * inv; wv.y = acc[2*q2+1] * inv;
            *(float2*)&sS2[tid * K2 + 2*q2] = wv;
        }
    }
    __syncthreads();

    // ---- p12: AS2 (waves 0-1) ; SS2+den2 (wave 2) ; X3 (wave 3) ----
    if (tid < 100) {             // AS2: (n, l-pair), f4 A2/srowm + f2 S2
        int n = tid / 5, lp = tid - (tid / 5) * 5;
        int l0 = 2 * lp;
        float accx = 0.f, accy = 0.f;
#pragma unroll
        for (int j = 0; j < 5; j++) {
            float4 av = *(const float4*)&sA2[n * K1 + 4*j];
            float4 rm = *(const float4*)&srowm[4*j];
            float2 s0 = *(const float2*)&sS2[(4*j+0) * K2 + l0];
            float2 s1 = *(const float2*)&sS2[(4*j+1) * K2 + l0];
            float2 s2v = *(const float2*)&sS2[(4*j+2) * K2 + l0];
            float2 s3 = *(const float2*)&sS2[(4*j+3) * K2 + l0];
            float c0 = av.x * rm.x, c1 = av.y * rm.y, c2 = av.z * rm.z, c3 = av.w * rm.w;
            accx = fmaf(c0, s0.x, accx); accy = fmaf(c0, s0.y, accy);
            accx = fmaf(c1, s1.x, accx); accy = fmaf(c1, s1.y, accy);
            accx = fmaf(c2, s2v.x, accx); accy = fmaf(c2, s2v.y, accy);
            accx = fmaf(c3, s3.x, accx); accy = fmaf(c3, s3.y, accy);
        }
        float cd = sA2[n * (K1 + 1)] * srowm[n];
        float2 sn = *(const float2*)&sS2[n * K2 + l0];
        accx -= cd * sn.x; accy -= cd * sn.y;
        float rn = srowm[n];
        float2 wv; wv.x = accx * rn; wv.y = accy * rn;
        *(float2*)&sAS2[n * K2 + l0] = wv;
    } else if (tid >= 128 && tid < 153) {   // SS2: (k-pair, l-pair)
        int oo = tid - 128;
        int kp = oo / 5, lp = oo - kp * 5;
        int k0 = 2 * kp, l0 = 2 * lp;
        float a00 = 0.f, a01 = 0.f, a10 = 0.f, a11 = 0.f;
#pragma unroll
        for (int n = 0; n < K1; n++) {
            float2 a = *(const float2*)&sS2[n * K2 + k0];
            float2 b = *(const float2*)&sS2[n * K2 + l0];
            a00 = fmaf(a.x, b.x, a00); a01 = fmaf(a.x, b.y, a01);
            a10 = fmaf(a.y, b.x, a10); a11 = fmaf(a.y, b.y, a11);
        }
        sSS[(k0+0) * K2 + l0]     = a00;
        sSS[(k0+0) * K2 + l0 + 1] = a01;
        sSS[(k0+1) * K2 + l0]     = a10;
        sSS[(k0+1) * K2 + l0 + 1] = a11;
    } else if (tid >= 160 && tid < 180) {   // den2 terms
        int n = tid - 160;
        float da = 0.f;
#pragma unroll
        for (int j = 0; j < 5; j++) {
            float4 av = *(const float4*)&sA2[n * K1 + 4*j];
            float4 rm = *(const float4*)&srowm[4*j];
            da = fmaf(av.x, rm.x, da); da = fmaf(av.y, rm.y, da);
            da = fmaf(av.z, rm.z, da); da = fmaf(av.w, rm.w, da);
        }
        da -= sA2[n * (K1 + 1)] * srowm[n];
        da *= srowm[n];
        float s2 = 0.f;
#pragma unroll
        for (int q2 = 0; q2 < 5; q2++) {
            float2 v = *(const float2*)&sS2[n * K2 + 2*q2];
            s2 = fmaf(v.x, v.x, s2); s2 = fmaf(v.y, v.y, s2);
        }
        sden[n] = da * s2;
    } else if (tid >= 192 && tid < 232) {   // X3 = S2^T X2' (2-k tiles)
        int oo = tid - 192;
        int kp = oo >> 3, fq = oo & 7;
        int k0 = 2 * kp;
        float4 acc0 = {0.f,0.f,0.f,0.f}, acc1 = {0.f,0.f,0.f,0.f};
#pragma unroll
        for (int n = 0; n < K1; n++) {
            float2 sv = *(const float2*)&sS2[n * K2 + k0];
            float4 bv = ((const float4*)(sX2 + n * SH))[fq];
            FMA4(acc0, sv.x, bv); FMA4(acc1, sv.y, bv);
        }
        ((float4*)(sX3 + (k0+0) * SH))[fq] = acc0;
        ((float4*)(sX3 + (k0+1) * SH))[fq] = acc1;
    }
    __syncthreads();

    // ---- p13: A3 = S2^T AS2 f2-tiled (wave0) ; den2 (w2) ; ortho2 (w3) ----
    if (tid < 25) {
        int kp = tid / 5, lp = tid - kp * 5;
        int k0 = 2 * kp, l0 = 2 * lp;
        float a00 = 0.f, a01 = 0.f, a10 = 0.f, a11 = 0.f;
#pragma unroll
        for (int n = 0; n < K1; n++) {
            float2 sv = *(const float2*)&sS2[n * K2 + k0];
            float2 av = *(const float2*)&sAS2[n * K2 + l0];
            a00 = fmaf(sv.x, av.x, a00); a01 = fmaf(sv.x, av.y, a01);
            a10 = fmaf(sv.y, av.x, a10); a11 = fmaf(sv.y, av.y, a11);
        }
        sA3[(k0+0) * K2 + l0]     = a00;
        sA3[(k0+0) * K2 + l0 + 1] = a01;
        sA3[(k0+1) * K2 + l0]     = a10;
        sA3[(k0+1) * K2 + l0 + 1] = a11;
    } else if (wid == 2) {
        float v = (lane < K1) ? sden[lane] : 0.f;
        v = wave_red(v);
        if (lane == 0) sc[5] = v;
    } else if (wid == 3) {
        float f = 0.f, tr = 0.f;
        for (int i = lane; i < K2 * K2; i += 64) {
            float t = sSS[i];
            f = fmaf(t, t, f);
            if (i % (K2 + 1) == 0) tr += t;
        }
        f = wave_red(f); tr = wave_red(tr);
        if (lane == 0)
            sc[6] = sqrtf(fmaxf(2.f - 2.f * tr / (sqrtf(f) * 3.1622776601683795f), 0.f));
    }
    __syncthreads();

    // ---- p14: XW3r/XW3o (f4 X3 reads) ; rownorm2 + loss (wave 3) ----
    if (tid < 160) {
        bool first = (tid < 80);
        int oo = first ? tid : tid - 80;
        int n = oo >> 3, fq = oo & 7;
        const float4* wg = (const float4*)(first ? w3r_ : w3o_);
        float4 acc = {0.f,0.f,0.f,0.f};
#pragma unroll
        for (int j = 0; j < 8; j++) {
            float4 a = ((const float4*)(sX3 + n * SH))[j];
            float4 w0 = wg[(4*j+0) * 8 + fq];
            float4 w1 = wg[(4*j+1) * 8 + fq];
            float4 w2 = wg[(4*j+2) * 8 + fq];
            float4 w3 = wg[(4*j+3) * 8 + fq];
            FMA4(acc, a.x, w0); FMA4(acc, a.y, w1);
            FMA4(acc, a.z, w2); FMA4(acc, a.w, w3);
        }
        if (first) ((float4*)(sW3r + n * SH))[fq] = acc;
        else       ((float4*)(sW3o + n * SH))[fq] = acc;
    } else if (tid >= 192 && tid < 202) {
        int l = tid - 192;
        float s = 0.f;
#pragma unroll
        for (int j = 0; j < 5; j++) {
            float2 a = *(const float2*)&sA3[l * K2 + 2*j];
            s += a.x + a.y;
        }
        s -= sA3[l * (K2 + 1)];
        srowm[l] = 1.f / (sqrtf(s) + EPSF);
    } else if (tid == 202) {
        float num2 = 0.f;
#pragma unroll
        for (int k = 0; k < K2; k++) num2 += sA3[k * (K2 + 1)];
        wsg[g] = -(sc[0] / sc[1]) + sc[2] - num2 / sc[5] + sc[6];
    }
    __syncthreads();

    // ---- p15: X4 = adj2n @ XW3r + XW3o + b3  [f2 A3/srowm, diag-sub] ----
    if (tid < 80) {
        int k = tid >> 3, fq = tid & 7;
        float4 acc = {0.f,0.f,0.f,0.f};
#pragma unroll
        for (int j = 0; j < 5; j++) {
            float2 av = *(const float2*)&sA3[k * K2 + 2*j];
            float2 rm = *(const float2*)&srowm[2*j];
            float c0 = av.x * rm.x, c1 = av.y * rm.y;
            float4 w0 = ((const float4*)(sW3r + (2*j+0) * SH))[fq];
            float4 w1 = ((const float4*)(sW3r + (2*j+1) * SH))[fq];
            FMA4(acc, c0, w0); FMA4(acc, c1, w1);
        }
        float adiag = sA3[k * (K2 + 1)] * srowm[k];
        float4 wk = ((const float4*)(sW3r + k * SH))[fq];
        acc.x -= adiag * wk.x; acc.y -= adiag * wk.y;
        acc.z -= adiag * wk.z; acc.w -= adiag * wk.w;
        float4 bb = ((const float4*)b3_)[fq];
        float4 oo = ((const float4*)(sW3o + k * SH))[fq];
        float rk = srowm[k];
        float4 r;
        r.x = fmaf(rk, acc.x, oo.x + bb.x);
        r.y = fmaf(rk, acc.y, oo.y + bb.y);
        r.z = fmaf(rk, acc.z, oo.z + bb.z);
        r.w = fmaf(rk, acc.w, oo.w + bb.w);
        ((float4*)(sX4 + k * SH))[fq] = r;
    }
    __syncthreads();

    // ---- p16: mean pool + MLP head (wave 0, shuffle-based) ----
    if (wid == 0) {
        int f = lane & 31;
        float pool = 0.f;
#pragma unroll
        for (int n = 0; n < K2; n++) pool += sX4[n * SH + f];
        pool *= (1.f / K2);
        float acc = b_l1[f];
#pragma unroll
        for (int j = 0; j < HID; j++)
            acc = fmaf(__shfl(pool, j, 64), w_l1[j * HID + f], acc);
        float t1 = fmaxf(acc, 0.f);
        int o = (lane < OUTC) ? lane : 0;
        float acc2 = b_l2[o];
#pragma unroll
        for (int j = 0; j < HID; j++)
            acc2 = fmaf(__shfl(t1, j, 64), w_l2[j * OUTC + o], acc2);
        if (lane < OUTC) out[(size_t)g * OUTC + lane] = acc2;
    }
}

__global__ void loss_reduce(const float* __restrict__ wsg, float* __restrict__ out)
{
    __shared__ float sred[4];
    int tid = threadIdx.x;
    float s = 0.f;
    for (int i = tid; i < Bg; i += NT) s += wsg[i];
    s = wave_red(s);
    if ((tid & 63) == 0) sred[tid >> 6] = s;
    __syncthreads();
    if (tid == 0) out[(size_t)Bg * OUTC] = (sred[0] + sred[1] + sred[2] + sred[3]) * (1.f / Bg);
}

extern "C" void kernel_launch(void* const* d_in, const int* in_sizes, int n_in,
                              void* d_out, int out_size, void* d_ws, size_t ws_size,
                              hipStream_t stream)
{
    const float* x    = (const float*)d_in[0];
    const int*   ei   = (const int*)  d_in[1];
    // d_in[2] = batch (unused: graphs are contiguous blocks of NPG nodes)
    const float* w_c1 = (const float*)d_in[3];
    const float* b_c1 = (const float*)d_in[4];
    const float* w_p1 = (const float*)d_in[5];
    const float* b_p1 = (const float*)d_in[6];
    const float* w2r  = (const float*)d_in[7];
    const float* b2   = (const float*)d_in[8];
    const float* w2o  = (const float*)d_in[9];
    const float* w_p2 = (const float*)d_in[10];
    const float* b_p2 = (const float*)d_in[11];
    const float* w3r  = (const float*)d_in[12];
    const float* b3   = (const float*)d_in[13];
    const float* w3o  = (const float*)d_in[14];
    const float* w_l1 = (const float*)d_in[15];
    const float* b_l1 = (const float*)d_in[16];
    const float* w_l2 = (const float*)d_in[17];
    const float* b_l2 = (const float*)d_in[18];
    float* out = (float*)d_out;
    float* wsg = (float*)d_ws;

    hipLaunchKernelGGL(mincut_fused, dim3(Bg), dim3(NT), 0, stream,
                       x, ei, w_c1, b_c1, w_p1, b_p1, w2r, b2, w2o,
                       w_p2, b_p2, w3r, b3, w3o, w_l1, b_l1, w_l2, b_l2,
                       out, wsg);
    hipLaunchKernelGGL(loss_reduce, dim3(1), dim3(NT), 0, stream, wsg, out);
}